// Round 1
// baseline (497.478 us; speedup 1.0000x reference)
//
#include <hip/hip_runtime.h>
#include <math.h>

#define NN 50000
#define EE 400000
#define INC 128
#define TD 16
#define H1C 256   // HEADS*HID
#define OUTC 32
#define NEG 0.2f

__device__ __forceinline__ float leaky(float x) { return x > 0.f ? x : NEG * x; }

// ---------------- time encoding + scatter-mean(src) ----------------
__global__ void k_time(const float* __restrict__ et, const int* __restrict__ ei,
                       const float* __restrict__ tw, const float* __restrict__ tb,
                       float* __restrict__ tsum, float* __restrict__ cnt) {
  int idx = blockIdx.x * 256 + threadIdx.x;
  if (idx >= EE * TD) return;
  int e = idx >> 4, k = idx & 15;
  float tp = et[e] * tw[k] + tb[k];
  float v = (k & 1) ? cosf(tp) : sinf(tp);
  int s = ei[e];  // src
  atomicAdd(&tsum[s * TD + k], v);
  if (k == 0) atomicAdd(&cnt[s], 1.0f);
}

// ---------------- CSR build over dst ----------------
__global__ void k_deg(const int* __restrict__ ei, int* __restrict__ deg) {
  int e = blockIdx.x * 256 + threadIdx.x;
  if (e < EE) atomicAdd(&deg[ei[EE + e]], 1);
}

__global__ void k_scan1(const int* __restrict__ deg, int* __restrict__ rowst,
                        int* __restrict__ bsum) {
  __shared__ int sh[1024];
  int tid = threadIdx.x;
  int i = blockIdx.x * 1024 + tid;
  int v = (i < NN) ? deg[i] : 0;
  sh[tid] = v;
  __syncthreads();
  for (int off = 1; off < 1024; off <<= 1) {
    int t = (tid >= off) ? sh[tid - off] : 0;
    __syncthreads();
    sh[tid] += t;
    __syncthreads();
  }
  if (i < NN) rowst[i] = sh[tid] - v;  // exclusive within block
  if (tid == 1023) bsum[blockIdx.x] = sh[1023];
}

__global__ void k_scan2(int* __restrict__ bsum, int nb) {
  int tid = threadIdx.x;  // 64 threads, one wave
  int v = (tid < nb) ? bsum[tid] : 0;
  int incl = v;
  #pragma unroll
  for (int off = 1; off < 64; off <<= 1) {
    int t = __shfl_up(incl, off);
    if (tid >= off) incl += t;
  }
  if (tid < nb) bsum[tid] = incl - v;  // exclusive block offsets
}

__global__ void k_scan3(int* __restrict__ rowst, const int* __restrict__ bsum) {
  int i = blockIdx.x * 256 + threadIdx.x;
  if (i < NN) rowst[i] += bsum[i >> 10];
  if (i == 0) rowst[NN] = EE;
}

__global__ void k_fill(const int* __restrict__ rowst, int* __restrict__ fill) {
  int i = blockIdx.x * 256 + threadIdx.x;
  if (i < NN) fill[i] = rowst[i];
}

__global__ void k_scatter(const int* __restrict__ ei, int* __restrict__ fill,
                          int* __restrict__ eidx) {
  int e = blockIdx.x * 256 + threadIdx.x;
  if (e >= EE) return;
  int d = ei[EE + e];
  int pos = atomicAdd(&fill[d], 1);
  eidx[pos] = e;
}

// ---------------- projection: xin = [x, node_time] @ proj_w + proj_b ----------------
__global__ void k_proj(const float* __restrict__ x, const float* __restrict__ tsum,
                       const float* __restrict__ cnt, const float* __restrict__ pw,
                       const float* __restrict__ pb, float* __restrict__ xin) {
  __shared__ float rows[16][144];
  int tid = threadIdx.x;
  int n0 = blockIdx.x * 16;
  for (int i = tid; i < 16 * 144; i += 256) {
    int rr = i / 144, k = i - rr * 144;
    int n = n0 + rr;
    float v = 0.f;
    if (n < NN) v = (k < 128) ? x[(size_t)n * INC + k]
                              : tsum[n * TD + (k - 128)] / (cnt[n] + 1.f);
    rows[rr][k] = v;
  }
  __syncthreads();
  int j = tid & 127, half = tid >> 7;
  int rbase = half * 8;
  float acc[8];
  #pragma unroll
  for (int r = 0; r < 8; ++r) acc[r] = 0.f;
  for (int k = 0; k < 144; ++k) {
    float wk = pw[k * 128 + j];
    #pragma unroll
    for (int r = 0; r < 8; ++r) acc[r] = fmaf(rows[rbase + r][k], wk, acc[r]);
  }
  float bj = pb[j];
  #pragma unroll
  for (int r = 0; r < 8; ++r) {
    int n = n0 + rbase + r;
    if (n < NN) xin[(size_t)n * INC + j] = acc[r] + bj;
  }
}

// ---------------- h1 = xin @ W1 ; al_s1/al_d1 head reductions ----------------
__global__ void k_h1(const float* __restrict__ xin, const float* __restrict__ W1,
                     const float* __restrict__ asrc, const float* __restrict__ adst,
                     float* __restrict__ h1, float* __restrict__ als,
                     float* __restrict__ ald) {
  __shared__ float rows[8][128];
  int tid = threadIdx.x;
  int n0 = blockIdx.x * 8;
  for (int i = tid; i < 8 * 128; i += 256)
    rows[i >> 7][i & 127] = xin[(size_t)(n0 + (i >> 7)) * INC + (i & 127)];
  __syncthreads();
  int j = tid;  // 256 cols
  float acc[8];
  #pragma unroll
  for (int r = 0; r < 8; ++r) acc[r] = 0.f;
  for (int k = 0; k < 128; ++k) {
    float wk = W1[k * H1C + j];
    #pragma unroll
    for (int r = 0; r < 8; ++r) acc[r] = fmaf(rows[r][k], wk, acc[r]);
  }
  float as_ = asrc[j], ad_ = adst[j];
  int lane = tid & 63, h = tid >> 6;
  #pragma unroll
  for (int r = 0; r < 8; ++r) {
    int n = n0 + r;
    h1[(size_t)n * H1C + j] = acc[r];
    float vs = acc[r] * as_, vd = acc[r] * ad_;
    #pragma unroll
    for (int o = 32; o >= 1; o >>= 1) {
      vs += __shfl_xor(vs, o);
      vd += __shfl_xor(vd, o);
    }
    if (lane == 0) { als[n * 4 + h] = vs; ald[n * 4 + h] = vd; }
  }
}

// ---------------- layer-1 softmax-aggregate + bias + ELU + LN (1 wave / node) ----------------
__global__ void k_agg1(const int* __restrict__ ei, const int* __restrict__ rowst,
                       const int* __restrict__ eidx, const float* __restrict__ h1,
                       const float* __restrict__ als, const float* __restrict__ ald,
                       const float* __restrict__ b1, const float* __restrict__ g1,
                       const float* __restrict__ be1, float* __restrict__ ln1) {
  int lane = threadIdx.x & 63;
  int n = blockIdx.x * 4 + (threadIdx.x >> 6);
  int k0 = rowst[n], k1 = rowst[n + 1];
  const float4 adv = *(const float4*)(ald + n * 4);
  const float4 asv = *(const float4*)(als + n * 4);
  float es0 = leaky(asv.x + adv.x), es1 = leaky(asv.y + adv.y);
  float es2 = leaky(asv.z + adv.z), es3 = leaky(asv.w + adv.w);
  float m0 = es0, m1 = es1, m2 = es2, m3 = es3;
  for (int i = k0 + lane; i < k1; i += 64) {
    int s = ei[eidx[i]];
    const float4 a = *(const float4*)(als + s * 4);
    m0 = fmaxf(m0, leaky(a.x + adv.x));
    m1 = fmaxf(m1, leaky(a.y + adv.y));
    m2 = fmaxf(m2, leaky(a.z + adv.z));
    m3 = fmaxf(m3, leaky(a.w + adv.w));
  }
  #pragma unroll
  for (int o = 32; o >= 1; o >>= 1) {
    m0 = fmaxf(m0, __shfl_xor(m0, o));
    m1 = fmaxf(m1, __shfl_xor(m1, o));
    m2 = fmaxf(m2, __shfl_xor(m2, o));
    m3 = fmaxf(m3, __shfl_xor(m3, o));
  }
  float d0 = 0.f, d1 = 0.f, d2 = 0.f, d3 = 0.f;
  for (int i = k0 + lane; i < k1; i += 64) {
    int s = ei[eidx[i]];
    const float4 a = *(const float4*)(als + s * 4);
    d0 += expf(leaky(a.x + adv.x) - m0);
    d1 += expf(leaky(a.y + adv.y) - m1);
    d2 += expf(leaky(a.z + adv.z) - m2);
    d3 += expf(leaky(a.w + adv.w) - m3);
  }
  #pragma unroll
  for (int o = 32; o >= 1; o >>= 1) {
    d0 += __shfl_xor(d0, o); d1 += __shfl_xor(d1, o);
    d2 += __shfl_xor(d2, o); d3 += __shfl_xor(d3, o);
  }
  d0 += expf(es0 - m0); d1 += expf(es1 - m1);
  d2 += expf(es2 - m2); d3 += expf(es3 - m3);

  int hh = lane >> 4;  // 4 channels/lane -> head = lane/16
  float mh  = hh == 0 ? m0 : hh == 1 ? m1 : hh == 2 ? m2 : m3;
  float dh  = hh == 0 ? d0 : hh == 1 ? d1 : hh == 2 ? d2 : d3;
  float adh = hh == 0 ? adv.x : hh == 1 ? adv.y : hh == 2 ? adv.z : adv.w;
  float esh = hh == 0 ? es0 : hh == 1 ? es1 : hh == 2 ? es2 : es3;
  float inv_dh = 1.f / dh;
  int c0 = lane * 4;
  float a_self = expf(esh - mh) * inv_dh;
  const float4 hv = *(const float4*)(h1 + (size_t)n * H1C + c0);
  float v0 = hv.x * a_self, v1 = hv.y * a_self, v2 = hv.z * a_self, v3 = hv.w * a_self;
  for (int i = k0; i < k1; ++i) {
    int s = ei[eidx[i]];
    float aa = expf(leaky(als[s * 4 + hh] + adh) - mh) * inv_dh;
    const float4 hg = *(const float4*)(h1 + (size_t)s * H1C + c0);
    v0 = fmaf(hg.x, aa, v0); v1 = fmaf(hg.y, aa, v1);
    v2 = fmaf(hg.z, aa, v2); v3 = fmaf(hg.w, aa, v3);
  }
  v0 += b1[c0 + 0]; v1 += b1[c0 + 1]; v2 += b1[c0 + 2]; v3 += b1[c0 + 3];
  v0 = v0 > 0.f ? v0 : expm1f(v0);
  v1 = v1 > 0.f ? v1 : expm1f(v1);
  v2 = v2 > 0.f ? v2 : expm1f(v2);
  v3 = v3 > 0.f ? v3 : expm1f(v3);
  float s1 = v0 + v1 + v2 + v3;
  float s2 = v0 * v0 + v1 * v1 + v2 * v2 + v3 * v3;
  #pragma unroll
  for (int o = 32; o >= 1; o >>= 1) {
    s1 += __shfl_xor(s1, o);
    s2 += __shfl_xor(s2, o);
  }
  float mu = s1 * (1.f / 256.f);
  float var = s2 * (1.f / 256.f) - mu * mu;
  float sc = rsqrtf(var + 1e-5f);
  float4 o4;
  o4.x = (v0 - mu) * sc * g1[c0 + 0] + be1[c0 + 0];
  o4.y = (v1 - mu) * sc * g1[c0 + 1] + be1[c0 + 1];
  o4.z = (v2 - mu) * sc * g1[c0 + 2] + be1[c0 + 2];
  o4.w = (v3 - mu) * sc * g1[c0 + 3] + be1[c0 + 3];
  *(float4*)(ln1 + (size_t)n * H1C + c0) = o4;
}

// ---------------- h2 = ln1 @ W2 ; al_s2/al_d2 ----------------
__global__ void k_h2(const float* __restrict__ ln1, const float* __restrict__ W2,
                     const float* __restrict__ aw_s, const float* __restrict__ aw_d,
                     float* __restrict__ h2, float* __restrict__ als2,
                     float* __restrict__ ald2) {
  __shared__ float Wl[256 * 32];
  __shared__ float rows[8][257];
  int tid = threadIdx.x;
  int n0 = blockIdx.x * 8;
  for (int i = tid; i < 256 * 32; i += 256) Wl[i] = W2[i];
  for (int i = tid; i < 8 * 256; i += 256)
    rows[i >> 8][i & 255] = ln1[(size_t)(n0 + (i >> 8)) * H1C + (i & 255)];
  __syncthreads();
  int r = tid >> 5, c = tid & 31;
  float acc = 0.f;
  for (int k = 0; k < 256; ++k) acc = fmaf(rows[r][k], Wl[k * 32 + c], acc);
  int n = n0 + r;
  h2[n * OUTC + c] = acc;
  float vs = acc * aw_s[c], vd = acc * aw_d[c];
  #pragma unroll
  for (int o = 16; o >= 1; o >>= 1) {
    vs += __shfl_xor(vs, o, 32);
    vd += __shfl_xor(vd, o, 32);
  }
  if (c == 0) { als2[n] = vs; ald2[n] = vd; }
}

// ---------------- layer-2 softmax-aggregate + bias + LN -> out ----------------
__global__ void k_agg2(const int* __restrict__ ei, const int* __restrict__ rowst,
                       const int* __restrict__ eidx, const float* __restrict__ h2,
                       const float* __restrict__ als2, const float* __restrict__ ald2,
                       const float* __restrict__ b2, const float* __restrict__ g2,
                       const float* __restrict__ be2, float* __restrict__ out) {
  int lane = threadIdx.x & 63;
  int n = blockIdx.x * 4 + (threadIdx.x >> 6);
  int k0 = rowst[n], k1 = rowst[n + 1];
  float ad = ald2[n];
  float es = leaky(als2[n] + ad);
  float m = es;
  for (int i = k0 + lane; i < k1; i += 64)
    m = fmaxf(m, leaky(als2[ei[eidx[i]]] + ad));
  #pragma unroll
  for (int o = 32; o >= 1; o >>= 1) m = fmaxf(m, __shfl_xor(m, o));
  float d = 0.f;
  for (int i = k0 + lane; i < k1; i += 64)
    d += expf(leaky(als2[ei[eidx[i]]] + ad) - m);
  #pragma unroll
  for (int o = 32; o >= 1; o >>= 1) d += __shfl_xor(d, o);
  d += expf(es - m);
  float inv_d = 1.f / d;
  int c = lane & 31;
  bool act = lane < 32;
  float acc = act ? h2[n * OUTC + c] * (expf(es - m) * inv_d) : 0.f;
  for (int i = k0; i < k1; ++i) {
    int s = ei[eidx[i]];
    float aa = expf(leaky(als2[s] + ad) - m) * inv_d;
    float hg = act ? h2[s * OUTC + c] : 0.f;
    acc = fmaf(hg, aa, acc);
  }
  if (act) {
    float v = acc + b2[c];
    float s1 = v, s2 = v * v;
    #pragma unroll
    for (int o = 16; o >= 1; o >>= 1) {
      s1 += __shfl_xor(s1, o, 32);
      s2 += __shfl_xor(s2, o, 32);
    }
    float mu = s1 * (1.f / 32.f);
    float var = s2 * (1.f / 32.f) - mu * mu;
    float sc = rsqrtf(var + 1e-5f);
    out[n * OUTC + c] = (v - mu) * sc * g2[c] + be2[c];
  }
}

extern "C" void kernel_launch(void* const* d_in, const int* in_sizes, int n_in,
                              void* d_out, int out_size, void* d_ws, size_t ws_size,
                              hipStream_t stream) {
  const float* x   = (const float*)d_in[0];
  const int*   ei  = (const int*)d_in[1];
  const float* et  = (const float*)d_in[2];
  const float* tw  = (const float*)d_in[3];
  const float* tb  = (const float*)d_in[4];
  const float* pw  = (const float*)d_in[5];
  const float* pb  = (const float*)d_in[6];
  const float* W1  = (const float*)d_in[7];
  const float* as1 = (const float*)d_in[8];
  const float* ad1 = (const float*)d_in[9];
  const float* b1  = (const float*)d_in[10];
  const float* g1  = (const float*)d_in[11];
  const float* be1 = (const float*)d_in[12];
  const float* W2  = (const float*)d_in[13];
  const float* as2 = (const float*)d_in[14];
  const float* ad2 = (const float*)d_in[15];
  const float* b2  = (const float*)d_in[16];
  const float* g2  = (const float*)d_in[17];
  const float* be2 = (const float*)d_in[18];

  char* ws = (char*)d_ws;
  size_t off = 0;
  auto alloc = [&](size_t bytes) {
    void* p = ws + off;
    off += (bytes + 255) & ~(size_t)255;
    return p;
  };
  float* tsum  = (float*)alloc((size_t)NN * TD * 4);
  float* cnt   = (float*)alloc((size_t)NN * 4);
  float* xin   = (float*)alloc((size_t)NN * INC * 4);
  float* h1    = (float*)alloc((size_t)NN * H1C * 4);
  float* als1v = (float*)alloc((size_t)NN * 4 * 4);
  float* ald1v = (float*)alloc((size_t)NN * 4 * 4);
  float* ln1   = (float*)alloc((size_t)NN * H1C * 4);
  float* h2    = (float*)alloc((size_t)NN * OUTC * 4);
  float* als2v = (float*)alloc((size_t)NN * 4);
  float* ald2v = (float*)alloc((size_t)NN * 4);
  int*   deg   = (int*)alloc((size_t)NN * 4);
  int*   rowst = (int*)alloc((size_t)(NN + 1) * 4);
  int*   fill  = (int*)alloc((size_t)NN * 4);
  int*   eidx  = (int*)alloc((size_t)EE * 4);
  int*   bsum  = (int*)alloc(64 * 4);

  hipMemsetAsync(tsum, 0, (size_t)NN * TD * 4, stream);
  hipMemsetAsync(cnt, 0, (size_t)NN * 4, stream);
  hipMemsetAsync(deg, 0, (size_t)NN * 4, stream);

  k_time<<<(EE * TD + 255) / 256, 256, 0, stream>>>(et, ei, tw, tb, tsum, cnt);
  k_deg<<<(EE + 255) / 256, 256, 0, stream>>>(ei, deg);
  k_scan1<<<(NN + 1023) / 1024, 1024, 0, stream>>>(deg, rowst, bsum);
  k_scan2<<<1, 64, 0, stream>>>(bsum, (NN + 1023) / 1024);
  k_scan3<<<(NN + 255) / 256, 256, 0, stream>>>(rowst, bsum);
  k_fill<<<(NN + 255) / 256, 256, 0, stream>>>(rowst, fill);
  k_scatter<<<(EE + 255) / 256, 256, 0, stream>>>(ei, fill, eidx);
  k_proj<<<(NN + 15) / 16, 256, 0, stream>>>(x, tsum, cnt, pw, pb, xin);
  k_h1<<<NN / 8, 256, 0, stream>>>(xin, W1, as1, ad1, h1, als1v, ald1v);
  k_agg1<<<NN / 4, 256, 0, stream>>>(ei, rowst, eidx, h1, als1v, ald1v, b1, g1, be1, ln1);
  k_h2<<<NN / 8, 256, 0, stream>>>(ln1, W2, as2, ad2, h2, als2v, ald2v);
  k_agg2<<<NN / 4, 256, 0, stream>>>(ei, rowst, eidx, h2, als2v, ald2v, b2, g2, be2,
                                     (float*)d_out);
}

// Round 2
// 444.413 us; speedup vs baseline: 1.1194x; 1.1194x over previous
//
#include <hip/hip_runtime.h>
#include <math.h>

#define NN 50000
#define EE 400000
#define INC 128
#define TD 16
#define H1C 256   // HEADS*HID
#define OUTC 32
#define NEG 0.2f

__device__ __forceinline__ float leaky(float x) { return x > 0.f ? x : NEG * x; }
__device__ __forceinline__ float sel4(const float4& v, int h) {
  return h == 0 ? v.x : h == 1 ? v.y : h == 2 ? v.z : v.w;
}

// ---------------- degree count (both directions) ----------------
__global__ void k_deg(const int* __restrict__ ei, int* __restrict__ deg_dst,
                      int* __restrict__ deg_src) {
  int e = blockIdx.x * 256 + threadIdx.x;
  if (e >= EE) return;
  atomicAdd(&deg_dst[ei[EE + e]], 1);
  atomicAdd(&deg_src[ei[e]], 1);
}

// ---------------- exclusive scan pipeline (run twice: dst, src) ----------------
__global__ void k_scan1(const int* __restrict__ deg, int* __restrict__ rowst,
                        int* __restrict__ bsum) {
  __shared__ int sh[1024];
  int tid = threadIdx.x;
  int i = blockIdx.x * 1024 + tid;
  int v = (i < NN) ? deg[i] : 0;
  sh[tid] = v;
  __syncthreads();
  for (int off = 1; off < 1024; off <<= 1) {
    int t = (tid >= off) ? sh[tid - off] : 0;
    __syncthreads();
    sh[tid] += t;
    __syncthreads();
  }
  if (i < NN) rowst[i] = sh[tid] - v;
  if (tid == 1023) bsum[blockIdx.x] = sh[1023];
}

__global__ void k_scan2(int* __restrict__ bsum, int nb) {
  int tid = threadIdx.x;  // one wave
  int v = (tid < nb) ? bsum[tid] : 0;
  int incl = v;
  #pragma unroll
  for (int off = 1; off < 64; off <<= 1) {
    int t = __shfl_up(incl, off);
    if (tid >= off) incl += t;
  }
  if (tid < nb) bsum[tid] = incl - v;
}

__global__ void k_scan3(int* __restrict__ rowst, const int* __restrict__ bsum,
                        int* __restrict__ fill) {
  int i = blockIdx.x * 256 + threadIdx.x;
  if (i < NN) {
    int r = rowst[i] + bsum[i >> 10];
    rowst[i] = r;
    fill[i] = r;
  }
  if (i == 0) rowst[NN] = EE;
}

// ---------------- scatter into both CSRs ----------------
__global__ void k_scatter(const int* __restrict__ ei, const float* __restrict__ et,
                          int* __restrict__ fill_dst, int* __restrict__ fill_src,
                          int* __restrict__ src_sorted, int* __restrict__ dst_sorted,
                          float* __restrict__ et_sorted) {
  int e = blockIdx.x * 256 + threadIdx.x;
  if (e >= EE) return;
  int s = ei[e], d = ei[EE + e];
  int p1 = atomicAdd(&fill_dst[d], 1);
  src_sorted[p1] = s;
  dst_sorted[p1] = d;
  int p2 = atomicAdd(&fill_src[s], 1);
  et_sorted[p2] = et[e];
}

// ---------------- time encoding, segmented mean over src-CSR ----------------
__global__ void k_time_agg(const int* __restrict__ rowst_src,
                           const float* __restrict__ et_sorted,
                           const float* __restrict__ tw, const float* __restrict__ tb,
                           float* __restrict__ node_time) {
  int lane = threadIdx.x & 63;
  int n = blockIdx.x * 4 + (threadIdx.x >> 6);
  int k0 = rowst_src[n], k1 = rowst_src[n + 1];
  int k = lane & 15, g = lane >> 4;
  float w = tw[k], b = tb[k];
  float v = 0.f;
  for (int i = k0 + g; i < k1; i += 4) {
    float tp = et_sorted[i] * w + b;
    v += (k & 1) ? cosf(tp) : sinf(tp);
  }
  v += __shfl_xor(v, 16);
  v += __shfl_xor(v, 32);
  if (lane < 16) node_time[n * TD + k] = v / (float)(k1 - k0 + 1);
}

// ---------------- projection: xin = [x, node_time] @ proj_w + proj_b ----------------
__global__ void k_proj(const float* __restrict__ x, const float* __restrict__ node_time,
                       const float* __restrict__ pw, const float* __restrict__ pb,
                       float* __restrict__ xin) {
  __shared__ float rows[16][144];
  int tid = threadIdx.x;
  int n0 = blockIdx.x * 16;
  for (int i = tid; i < 16 * 144; i += 256) {
    int rr = i / 144, k = i - rr * 144;
    int n = n0 + rr;
    float v = 0.f;
    if (n < NN) v = (k < 128) ? x[(size_t)n * INC + k] : node_time[n * TD + (k - 128)];
    rows[rr][k] = v;
  }
  __syncthreads();
  int j = tid & 127, half = tid >> 7;
  int rbase = half * 8;
  float acc[8];
  #pragma unroll
  for (int r = 0; r < 8; ++r) acc[r] = 0.f;
  for (int k = 0; k < 144; ++k) {
    float wk = pw[k * 128 + j];
    #pragma unroll
    for (int r = 0; r < 8; ++r) acc[r] = fmaf(rows[rbase + r][k], wk, acc[r]);
  }
  float bj = pb[j];
  #pragma unroll
  for (int r = 0; r < 8; ++r) {
    int n = n0 + rbase + r;
    if (n < NN) xin[(size_t)n * INC + j] = acc[r] + bj;
  }
}

// ---------------- h1 = xin @ W1 ; al_s1/al_d1 head reductions ----------------
__global__ void k_h1(const float* __restrict__ xin, const float* __restrict__ W1,
                     const float* __restrict__ asrc, const float* __restrict__ adst,
                     float* __restrict__ h1, float* __restrict__ als,
                     float* __restrict__ ald) {
  __shared__ float rows[8][128];
  int tid = threadIdx.x;
  int n0 = blockIdx.x * 8;
  for (int i = tid; i < 8 * 128; i += 256)
    rows[i >> 7][i & 127] = xin[(size_t)(n0 + (i >> 7)) * INC + (i & 127)];
  __syncthreads();
  int j = tid;  // 256 cols
  float acc[8];
  #pragma unroll
  for (int r = 0; r < 8; ++r) acc[r] = 0.f;
  for (int k = 0; k < 128; ++k) {
    float wk = W1[k * H1C + j];
    #pragma unroll
    for (int r = 0; r < 8; ++r) acc[r] = fmaf(rows[r][k], wk, acc[r]);
  }
  float as_ = asrc[j], ad_ = adst[j];
  int lane = tid & 63, h = tid >> 6;
  #pragma unroll
  for (int r = 0; r < 8; ++r) {
    int n = n0 + r;
    h1[(size_t)n * H1C + j] = acc[r];
    float vs = acc[r] * as_, vd = acc[r] * ad_;
    #pragma unroll
    for (int o = 32; o >= 1; o >>= 1) {
      vs += __shfl_xor(vs, o);
      vd += __shfl_xor(vd, o);
    }
    if (lane == 0) { als[n * 4 + h] = vs; ald[n * 4 + h] = vd; }
  }
}

// ---------------- per-edge layer-1 scores (CSR order) ----------------
__global__ void k_score1(const int* __restrict__ src_sorted,
                         const int* __restrict__ dst_sorted,
                         const float* __restrict__ als, const float* __restrict__ ald,
                         float* __restrict__ scores1) {
  int p = blockIdx.x * 256 + threadIdx.x;
  if (p >= EE) return;
  int s = src_sorted[p], d = dst_sorted[p];
  const float4 a = *(const float4*)(als + s * 4);
  const float4 b = *(const float4*)(ald + d * 4);
  float4 sc;
  sc.x = leaky(a.x + b.x);
  sc.y = leaky(a.y + b.y);
  sc.z = leaky(a.z + b.z);
  sc.w = leaky(a.w + b.w);
  *(float4*)(scores1 + (size_t)p * 4) = sc;
}

// ---------------- layer-1 softmax-aggregate + bias + ELU + LN ----------------
__global__ void k_agg1(const int* __restrict__ rowst, const int* __restrict__ src_sorted,
                       const float* __restrict__ scores1, const float* __restrict__ h1,
                       const float* __restrict__ als, const float* __restrict__ ald,
                       const float* __restrict__ b1, const float* __restrict__ g1,
                       const float* __restrict__ be1, float* __restrict__ ln1) {
  int lane = threadIdx.x & 63;
  int n = blockIdx.x * 4 + (threadIdx.x >> 6);
  int k0 = rowst[n], k1 = rowst[n + 1];
  const float4 adv = *(const float4*)(ald + n * 4);
  const float4 asv = *(const float4*)(als + n * 4);
  float4 es;
  es.x = leaky(asv.x + adv.x); es.y = leaky(asv.y + adv.y);
  es.z = leaky(asv.z + adv.z); es.w = leaky(asv.w + adv.w);
  float m0 = es.x, m1 = es.y, m2 = es.z, m3 = es.w;
  for (int i = k0 + lane; i < k1; i += 64) {
    const float4 sc = *(const float4*)(scores1 + (size_t)i * 4);
    m0 = fmaxf(m0, sc.x); m1 = fmaxf(m1, sc.y);
    m2 = fmaxf(m2, sc.z); m3 = fmaxf(m3, sc.w);
  }
  #pragma unroll
  for (int o = 32; o >= 1; o >>= 1) {
    m0 = fmaxf(m0, __shfl_xor(m0, o));
    m1 = fmaxf(m1, __shfl_xor(m1, o));
    m2 = fmaxf(m2, __shfl_xor(m2, o));
    m3 = fmaxf(m3, __shfl_xor(m3, o));
  }
  float d0 = 0.f, d1 = 0.f, d2 = 0.f, d3 = 0.f;
  for (int i = k0 + lane; i < k1; i += 64) {
    const float4 sc = *(const float4*)(scores1 + (size_t)i * 4);
    d0 += expf(sc.x - m0); d1 += expf(sc.y - m1);
    d2 += expf(sc.z - m2); d3 += expf(sc.w - m3);
  }
  #pragma unroll
  for (int o = 32; o >= 1; o >>= 1) {
    d0 += __shfl_xor(d0, o); d1 += __shfl_xor(d1, o);
    d2 += __shfl_xor(d2, o); d3 += __shfl_xor(d3, o);
  }
  d0 += expf(es.x - m0); d1 += expf(es.y - m1);
  d2 += expf(es.z - m2); d3 += expf(es.w - m3);

  int hh = lane >> 4;
  float mh = hh == 0 ? m0 : hh == 1 ? m1 : hh == 2 ? m2 : m3;
  float dh = hh == 0 ? d0 : hh == 1 ? d1 : hh == 2 ? d2 : d3;
  float inv_dh = 1.f / dh;
  int c0 = lane * 4;
  float a_self = expf(sel4(es, hh) - mh) * inv_dh;
  const float4 hv = *(const float4*)(h1 + (size_t)n * H1C + c0);
  float v0 = hv.x * a_self, v1 = hv.y * a_self, v2 = hv.z * a_self, v3 = hv.w * a_self;
  for (int base = k0; base < k1; base += 64) {
    int p = base + lane;
    int sv = (p < k1) ? src_sorted[p] : 0;
    int lim = min(64, k1 - base);
    for (int j = 0; j < lim; ++j) {
      int s = __shfl(sv, j);
      const float4 sc = *(const float4*)(scores1 + (size_t)(base + j) * 4);
      float aa = expf(sel4(sc, hh) - mh) * inv_dh;
      const float4 hg = *(const float4*)(h1 + (size_t)s * H1C + c0);
      v0 = fmaf(hg.x, aa, v0); v1 = fmaf(hg.y, aa, v1);
      v2 = fmaf(hg.z, aa, v2); v3 = fmaf(hg.w, aa, v3);
    }
  }
  v0 += b1[c0 + 0]; v1 += b1[c0 + 1]; v2 += b1[c0 + 2]; v3 += b1[c0 + 3];
  v0 = v0 > 0.f ? v0 : expm1f(v0);
  v1 = v1 > 0.f ? v1 : expm1f(v1);
  v2 = v2 > 0.f ? v2 : expm1f(v2);
  v3 = v3 > 0.f ? v3 : expm1f(v3);
  float s1 = v0 + v1 + v2 + v3;
  float s2 = v0 * v0 + v1 * v1 + v2 * v2 + v3 * v3;
  #pragma unroll
  for (int o = 32; o >= 1; o >>= 1) {
    s1 += __shfl_xor(s1, o);
    s2 += __shfl_xor(s2, o);
  }
  float mu = s1 * (1.f / 256.f);
  float var = s2 * (1.f / 256.f) - mu * mu;
  float sc_ = rsqrtf(var + 1e-5f);
  float4 o4;
  o4.x = (v0 - mu) * sc_ * g1[c0 + 0] + be1[c0 + 0];
  o4.y = (v1 - mu) * sc_ * g1[c0 + 1] + be1[c0 + 1];
  o4.z = (v2 - mu) * sc_ * g1[c0 + 2] + be1[c0 + 2];
  o4.w = (v3 - mu) * sc_ * g1[c0 + 3] + be1[c0 + 3];
  *(float4*)(ln1 + (size_t)n * H1C + c0) = o4;
}

// ---------------- h2 = ln1 @ W2 ; al_s2/al_d2 ----------------
__global__ void k_h2(const float* __restrict__ ln1, const float* __restrict__ W2,
                     const float* __restrict__ aw_s, const float* __restrict__ aw_d,
                     float* __restrict__ h2, float* __restrict__ als2,
                     float* __restrict__ ald2) {
  __shared__ float Wl[256 * 32];
  __shared__ float rows[8][257];
  int tid = threadIdx.x;
  int n0 = blockIdx.x * 8;
  for (int i = tid; i < 256 * 32; i += 256) Wl[i] = W2[i];
  for (int i = tid; i < 8 * 256; i += 256)
    rows[i >> 8][i & 255] = ln1[(size_t)(n0 + (i >> 8)) * H1C + (i & 255)];
  __syncthreads();
  int r = tid >> 5, c = tid & 31;
  float acc = 0.f;
  for (int k = 0; k < 256; ++k) acc = fmaf(rows[r][k], Wl[k * 32 + c], acc);
  int n = n0 + r;
  h2[n * OUTC + c] = acc;
  float vs = acc * aw_s[c], vd = acc * aw_d[c];
  #pragma unroll
  for (int o = 16; o >= 1; o >>= 1) {
    vs += __shfl_xor(vs, o, 32);
    vd += __shfl_xor(vd, o, 32);
  }
  if (c == 0) { als2[n] = vs; ald2[n] = vd; }
}

// ---------------- per-edge layer-2 scores ----------------
__global__ void k_score2(const int* __restrict__ src_sorted,
                         const int* __restrict__ dst_sorted,
                         const float* __restrict__ als2, const float* __restrict__ ald2,
                         float* __restrict__ score2) {
  int p = blockIdx.x * 256 + threadIdx.x;
  if (p >= EE) return;
  score2[p] = leaky(als2[src_sorted[p]] + ald2[dst_sorted[p]]);
}

// ---------------- layer-2 softmax-aggregate + bias + LN -> out ----------------
__global__ void k_agg2(const int* __restrict__ rowst, const int* __restrict__ src_sorted,
                       const float* __restrict__ score2, const float* __restrict__ h2,
                       const float* __restrict__ als2, const float* __restrict__ ald2,
                       const float* __restrict__ b2, const float* __restrict__ g2,
                       const float* __restrict__ be2, float* __restrict__ out) {
  int lane = threadIdx.x & 63;
  int n = blockIdx.x * 4 + (threadIdx.x >> 6);
  int k0 = rowst[n], k1 = rowst[n + 1];
  float es = leaky(als2[n] + ald2[n]);
  float m = es;
  for (int i = k0 + lane; i < k1; i += 64) m = fmaxf(m, score2[i]);
  #pragma unroll
  for (int o = 32; o >= 1; o >>= 1) m = fmaxf(m, __shfl_xor(m, o));
  float d = 0.f;
  for (int i = k0 + lane; i < k1; i += 64) d += expf(score2[i] - m);
  #pragma unroll
  for (int o = 32; o >= 1; o >>= 1) d += __shfl_xor(d, o);
  d += expf(es - m);
  float inv_d = 1.f / d;
  int c = lane & 31, g = lane >> 5;
  float acc = (g == 0) ? h2[n * OUTC + c] * (expf(es - m) * inv_d) : 0.f;
  for (int base = k0; base < k1; base += 64) {
    int p = base + lane;
    int sv = (p < k1) ? src_sorted[p] : 0;
    int lim = min(64, k1 - base);
    for (int j = g; j < lim; j += 2) {
      int s = __shfl(sv, j);
      float aa = expf(score2[base + j] - m) * inv_d;
      acc = fmaf(h2[s * OUTC + c], aa, acc);
    }
  }
  acc += __shfl_xor(acc, 32);
  if (g == 0) {
    float v = acc + b2[c];
    float s1 = v, s2 = v * v;
    #pragma unroll
    for (int o = 16; o >= 1; o >>= 1) {
      s1 += __shfl_xor(s1, o, 32);
      s2 += __shfl_xor(s2, o, 32);
    }
    float mu = s1 * (1.f / 32.f);
    float var = s2 * (1.f / 32.f) - mu * mu;
    float sc = rsqrtf(var + 1e-5f);
    out[n * OUTC + c] = (v - mu) * sc * g2[c] + be2[c];
  }
}

extern "C" void kernel_launch(void* const* d_in, const int* in_sizes, int n_in,
                              void* d_out, int out_size, void* d_ws, size_t ws_size,
                              hipStream_t stream) {
  const float* x   = (const float*)d_in[0];
  const int*   ei  = (const int*)d_in[1];
  const float* et  = (const float*)d_in[2];
  const float* tw  = (const float*)d_in[3];
  const float* tb  = (const float*)d_in[4];
  const float* pw  = (const float*)d_in[5];
  const float* pb  = (const float*)d_in[6];
  const float* W1  = (const float*)d_in[7];
  const float* as1 = (const float*)d_in[8];
  const float* ad1 = (const float*)d_in[9];
  const float* b1  = (const float*)d_in[10];
  const float* g1  = (const float*)d_in[11];
  const float* be1 = (const float*)d_in[12];
  const float* W2  = (const float*)d_in[13];
  const float* as2 = (const float*)d_in[14];
  const float* ad2 = (const float*)d_in[15];
  const float* b2  = (const float*)d_in[16];
  const float* g2  = (const float*)d_in[17];
  const float* be2 = (const float*)d_in[18];

  char* ws = (char*)d_ws;
  size_t off = 0;
  auto alloc = [&](size_t bytes) {
    void* p = ws + off;
    off += (bytes + 255) & ~(size_t)255;
    return p;
  };
  float* node_time = (float*)alloc((size_t)NN * TD * 4);
  float* xin   = (float*)alloc((size_t)NN * INC * 4);
  float* h1    = (float*)alloc((size_t)NN * H1C * 4);
  float* als1v = (float*)alloc((size_t)NN * 4 * 4);
  float* ald1v = (float*)alloc((size_t)NN * 4 * 4);
  float* ln1   = (float*)alloc((size_t)NN * H1C * 4);
  float* h2    = (float*)alloc((size_t)NN * OUTC * 4);
  float* als2v = (float*)alloc((size_t)NN * 4);
  float* ald2v = (float*)alloc((size_t)NN * 4);
  float* scores1 = (float*)alloc((size_t)EE * 4 * 4);
  float* score2  = (float*)alloc((size_t)EE * 4);
  float* et_sorted = (float*)alloc((size_t)EE * 4);
  int* deg_dst = (int*)alloc((size_t)NN * 4);
  int* deg_src = (int*)alloc((size_t)NN * 4);
  int* rowst_dst = (int*)alloc((size_t)(NN + 1) * 4);
  int* rowst_src = (int*)alloc((size_t)(NN + 1) * 4);
  int* fill_dst = (int*)alloc((size_t)NN * 4);
  int* fill_src = (int*)alloc((size_t)NN * 4);
  int* src_sorted = (int*)alloc((size_t)EE * 4);
  int* dst_sorted = (int*)alloc((size_t)EE * 4);
  int* bsum_d = (int*)alloc(64 * 4);
  int* bsum_s = (int*)alloc(64 * 4);

  hipMemsetAsync(deg_dst, 0, (size_t)NN * 4, stream);
  hipMemsetAsync(deg_src, 0, (size_t)NN * 4, stream);

  const int NB = (NN + 1023) / 1024;  // 49
  k_deg<<<(EE + 255) / 256, 256, 0, stream>>>(ei, deg_dst, deg_src);
  k_scan1<<<NB, 1024, 0, stream>>>(deg_dst, rowst_dst, bsum_d);
  k_scan1<<<NB, 1024, 0, stream>>>(deg_src, rowst_src, bsum_s);
  k_scan2<<<1, 64, 0, stream>>>(bsum_d, NB);
  k_scan2<<<1, 64, 0, stream>>>(bsum_s, NB);
  k_scan3<<<(NN + 255) / 256, 256, 0, stream>>>(rowst_dst, bsum_d, fill_dst);
  k_scan3<<<(NN + 255) / 256, 256, 0, stream>>>(rowst_src, bsum_s, fill_src);
  k_scatter<<<(EE + 255) / 256, 256, 0, stream>>>(ei, et, fill_dst, fill_src,
                                                  src_sorted, dst_sorted, et_sorted);
  k_time_agg<<<NN / 4, 256, 0, stream>>>(rowst_src, et_sorted, tw, tb, node_time);
  k_proj<<<(NN + 15) / 16, 256, 0, stream>>>(x, node_time, pw, pb, xin);
  k_h1<<<NN / 8, 256, 0, stream>>>(xin, W1, as1, ad1, h1, als1v, ald1v);
  k_score1<<<(EE + 255) / 256, 256, 0, stream>>>(src_sorted, dst_sorted, als1v, ald1v, scores1);
  k_agg1<<<NN / 4, 256, 0, stream>>>(rowst_dst, src_sorted, scores1, h1, als1v, ald1v,
                                     b1, g1, be1, ln1);
  k_h2<<<NN / 8, 256, 0, stream>>>(ln1, W2, as2, ad2, h2, als2v, ald2v);
  k_score2<<<(EE + 255) / 256, 256, 0, stream>>>(src_sorted, dst_sorted, als2v, ald2v, score2);
  k_agg2<<<NN / 4, 256, 0, stream>>>(rowst_dst, src_sorted, score2, h2, als2v, ald2v,
                                     b2, g2, be2, (float*)d_out);
}

// Round 3
// 311.080 us; speedup vs baseline: 1.5992x; 1.4286x over previous
//
#include <hip/hip_runtime.h>
#include <math.h>

#define NN 50000
#define EE 400000
#define INC 128
#define TD 16
#define H1C 256   // HEADS*HID
#define OUTC 32
#define NEG 0.2f

typedef _Float16 f16;
typedef __attribute__((ext_vector_type(8))) _Float16 f16x8;
typedef __attribute__((ext_vector_type(4))) _Float16 f16x4;
typedef __attribute__((ext_vector_type(4))) float f32x4;

__device__ __forceinline__ float leaky(float x) { return x > 0.f ? x : NEG * x; }
__device__ __forceinline__ float sel4(const float4& v, int h) {
  return h == 0 ? v.x : h == 1 ? v.y : h == 2 ? v.z : v.w;
}

// ---------------- degree count (both directions) ----------------
__global__ void k_deg(const int* __restrict__ ei, int* __restrict__ deg_dst,
                      int* __restrict__ deg_src) {
  int e = blockIdx.x * 256 + threadIdx.x;
  if (e >= EE) return;
  atomicAdd(&deg_dst[ei[EE + e]], 1);
  atomicAdd(&deg_src[ei[e]], 1);
}

__global__ void k_scan1(const int* __restrict__ deg, int* __restrict__ rowst,
                        int* __restrict__ bsum) {
  __shared__ int sh[1024];
  int tid = threadIdx.x;
  int i = blockIdx.x * 1024 + tid;
  int v = (i < NN) ? deg[i] : 0;
  sh[tid] = v;
  __syncthreads();
  for (int off = 1; off < 1024; off <<= 1) {
    int t = (tid >= off) ? sh[tid - off] : 0;
    __syncthreads();
    sh[tid] += t;
    __syncthreads();
  }
  if (i < NN) rowst[i] = sh[tid] - v;
  if (tid == 1023) bsum[blockIdx.x] = sh[1023];
}

__global__ void k_scan2(int* __restrict__ bsum, int nb) {
  int tid = threadIdx.x;  // one wave
  int v = (tid < nb) ? bsum[tid] : 0;
  int incl = v;
  #pragma unroll
  for (int off = 1; off < 64; off <<= 1) {
    int t = __shfl_up(incl, off);
    if (tid >= off) incl += t;
  }
  if (tid < nb) bsum[tid] = incl - v;
}

__global__ void k_scan3(int* __restrict__ rowst, const int* __restrict__ bsum,
                        int* __restrict__ fill) {
  int i = blockIdx.x * 256 + threadIdx.x;
  if (i < NN) {
    int r = rowst[i] + bsum[i >> 10];
    rowst[i] = r;
    fill[i] = r;
  }
  if (i == 0) rowst[NN] = EE;
}

__global__ void k_scatter(const int* __restrict__ ei, const float* __restrict__ et,
                          int* __restrict__ fill_dst, int* __restrict__ fill_src,
                          int* __restrict__ src_sorted, int* __restrict__ dst_sorted,
                          float* __restrict__ et_sorted) {
  int e = blockIdx.x * 256 + threadIdx.x;
  if (e >= EE) return;
  int s = ei[e], d = ei[EE + e];
  int p1 = atomicAdd(&fill_dst[d], 1);
  src_sorted[p1] = s;
  dst_sorted[p1] = d;
  int p2 = atomicAdd(&fill_src[s], 1);
  et_sorted[p2] = et[e];
}

// ---------------- time encoding, segmented mean over src-CSR ----------------
__global__ void k_time_agg(const int* __restrict__ rowst_src,
                           const float* __restrict__ et_sorted,
                           const float* __restrict__ tw, const float* __restrict__ tb,
                           float* __restrict__ node_time) {
  int lane = threadIdx.x & 63;
  int n = blockIdx.x * 4 + (threadIdx.x >> 6);
  int k0 = rowst_src[n], k1 = rowst_src[n + 1];
  int k = lane & 15, g = lane >> 4;
  float w = tw[k], b = tb[k];
  float v = 0.f;
  for (int i = k0 + g; i < k1; i += 4) {
    float tp = et_sorted[i] * w + b;
    v += (k & 1) ? cosf(tp) : sinf(tp);
  }
  v += __shfl_xor(v, 16);
  v += __shfl_xor(v, 32);
  if (lane < 16) node_time[n * TD + k] = v / (float)(k1 - k0 + 1);
}

// ---------------- weight prep: transpose + f16 convert ----------------
__global__ void k_prep(const float* __restrict__ W1, const float* __restrict__ pw,
                       const float* __restrict__ W2, f16* __restrict__ W1T,
                       f16* __restrict__ pwT, f16* __restrict__ W2T) {
  int idx = blockIdx.x * 256 + threadIdx.x;
  if (idx < 32768) {
    int c = idx >> 7, k = idx & 127;
    W1T[idx] = (f16)W1[k * 256 + c];
  }
  int i2 = idx - 32768;
  if (i2 >= 0 && i2 < 20480) {
    int c = i2 / 160, kp = i2 - c * 160;
    pwT[i2] = (f16)(kp < 144 ? pw[kp * 128 + c] : 0.f);
  }
  int i3 = idx - 53248;
  if (i3 >= 0 && i3 < 8192) {
    int c = i3 >> 8, k = i3 & 255;
    W2T[i3] = (f16)W2[k * 32 + c];
  }
}

// ---------------- MFMA proj: xin = [x|node_time] @ pw + pb  (f16 out) ----------------
__global__ __launch_bounds__(256) void k_projg(const float* __restrict__ x,
                                               const float* __restrict__ node_time,
                                               const f16* __restrict__ pwT,
                                               const float* __restrict__ pb,
                                               f16* __restrict__ xin) {
  __shared__ f16 A[64 * 168];  // 64 rows x 160 k (pad 8)
  int tid = threadIdx.x, l = tid & 63, w = tid >> 6;
  int n0 = blockIdx.x * 64;
  for (int idx = tid; idx < 64 * 160; idx += 256) {
    int r = idx / 160, c = idx - r * 160;
    int n = n0 + r;
    float v = 0.f;
    if (n < NN) v = (c < 128) ? x[(size_t)n * INC + c]
                              : (c < 144 ? node_time[n * TD + (c - 128)] : 0.f);
    A[r * 168 + c] = (f16)v;
  }
  int r16 = l & 15, g = l >> 4;
  f16x8 breg[2][5];
  #pragma unroll
  for (int jj = 0; jj < 2; ++jj) {
    int col = w * 32 + jj * 16 + r16;
    #pragma unroll
    for (int kk = 0; kk < 5; ++kk)
      breg[jj][kk] = *(const f16x8*)(pwT + col * 160 + kk * 32 + g * 8);
  }
  f32x4 acc[4][2];
  #pragma unroll
  for (int i = 0; i < 4; ++i)
    #pragma unroll
    for (int jj = 0; jj < 2; ++jj) acc[i][jj] = (f32x4){0.f, 0.f, 0.f, 0.f};
  __syncthreads();
  #pragma unroll
  for (int kk = 0; kk < 5; ++kk) {
    #pragma unroll
    for (int i = 0; i < 4; ++i) {
      f16x8 a = *(const f16x8*)(A + (i * 16 + r16) * 168 + kk * 32 + g * 8);
      acc[i][0] = __builtin_amdgcn_mfma_f32_16x16x32_f16(a, breg[0][kk], acc[i][0], 0, 0, 0);
      acc[i][1] = __builtin_amdgcn_mfma_f32_16x16x32_f16(a, breg[1][kk], acc[i][1], 0, 0, 0);
    }
  }
  #pragma unroll
  for (int i = 0; i < 4; ++i)
    #pragma unroll
    for (int jj = 0; jj < 2; ++jj) {
      int col = w * 32 + jj * 16 + r16;
      float bj = pb[col];
      #pragma unroll
      for (int q = 0; q < 4; ++q) {
        int row = n0 + i * 16 + g * 4 + q;
        if (row < NN) xin[(size_t)row * INC + col] = (f16)(acc[i][jj][q] + bj);
      }
    }
}

// ---------------- MFMA h1 = xin @ W1 (f16 out) ----------------
__global__ __launch_bounds__(256) void k_h1g(const f16* __restrict__ xin,
                                             const f16* __restrict__ W1T,
                                             f16* __restrict__ h1) {
  __shared__ f16 A[64 * 136];  // 64 x 128 (pad 8)
  int tid = threadIdx.x, l = tid & 63, w = tid >> 6;
  int n0 = blockIdx.x * 64;
  f16x8 zero = {};
  for (int ci = tid; ci < 1024; ci += 256) {
    int r = ci >> 4, c8 = (ci & 15) * 8;
    int n = n0 + r;
    f16x8 v = (n < NN) ? *(const f16x8*)(xin + (size_t)n * INC + c8) : zero;
    *(f16x8*)(A + r * 136 + c8) = v;
  }
  int r16 = l & 15, g = l >> 4;
  f16x8 breg[4][4];
  #pragma unroll
  for (int jj = 0; jj < 4; ++jj) {
    int col = w * 64 + jj * 16 + r16;
    #pragma unroll
    for (int kk = 0; kk < 4; ++kk)
      breg[jj][kk] = *(const f16x8*)(W1T + col * 128 + kk * 32 + g * 8);
  }
  f32x4 acc[4][4];
  #pragma unroll
  for (int i = 0; i < 4; ++i)
    #pragma unroll
    for (int jj = 0; jj < 4; ++jj) acc[i][jj] = (f32x4){0.f, 0.f, 0.f, 0.f};
  __syncthreads();
  #pragma unroll
  for (int kk = 0; kk < 4; ++kk)
    #pragma unroll
    for (int i = 0; i < 4; ++i) {
      f16x8 a = *(const f16x8*)(A + (i * 16 + r16) * 136 + kk * 32 + g * 8);
      #pragma unroll
      for (int jj = 0; jj < 4; ++jj)
        acc[i][jj] = __builtin_amdgcn_mfma_f32_16x16x32_f16(a, breg[jj][kk], acc[i][jj], 0, 0, 0);
    }
  #pragma unroll
  for (int i = 0; i < 4; ++i)
    #pragma unroll
    for (int jj = 0; jj < 4; ++jj) {
      int col = w * 64 + jj * 16 + r16;
      #pragma unroll
      for (int q = 0; q < 4; ++q) {
        int row = n0 + i * 16 + g * 4 + q;
        if (row < NN) h1[(size_t)row * H1C + col] = (f16)acc[i][jj][q];
      }
    }
}

// ---------------- MFMA h2 = ln1 @ W2 (f32 out) ----------------
__global__ __launch_bounds__(256) void k_h2g(const f16* __restrict__ ln1,
                                             const f16* __restrict__ W2T,
                                             float* __restrict__ h2) {
  __shared__ f16 A[64 * 264];  // 64 x 256 (pad 8)
  int tid = threadIdx.x, l = tid & 63, w = tid >> 6;
  int n0 = blockIdx.x * 64;
  f16x8 zero = {};
  for (int ci = tid; ci < 2048; ci += 256) {
    int r = ci >> 5, c8 = (ci & 31) * 8;
    int n = n0 + r;
    f16x8 v = (n < NN) ? *(const f16x8*)(ln1 + (size_t)n * H1C + c8) : zero;
    *(f16x8*)(A + r * 264 + c8) = v;
  }
  int r16 = l & 15, g = l >> 4;
  f16x8 breg[2][8];
  #pragma unroll
  for (int jj = 0; jj < 2; ++jj) {
    int col = jj * 16 + r16;
    #pragma unroll
    for (int kk = 0; kk < 8; ++kk)
      breg[jj][kk] = *(const f16x8*)(W2T + col * 256 + kk * 32 + g * 8);
  }
  f32x4 acc[2];
  acc[0] = (f32x4){0.f, 0.f, 0.f, 0.f};
  acc[1] = (f32x4){0.f, 0.f, 0.f, 0.f};
  __syncthreads();
  #pragma unroll
  for (int kk = 0; kk < 8; ++kk) {
    f16x8 a = *(const f16x8*)(A + (w * 16 + r16) * 264 + kk * 32 + g * 8);
    acc[0] = __builtin_amdgcn_mfma_f32_16x16x32_f16(a, breg[0][kk], acc[0], 0, 0, 0);
    acc[1] = __builtin_amdgcn_mfma_f32_16x16x32_f16(a, breg[1][kk], acc[1], 0, 0, 0);
  }
  #pragma unroll
  for (int jj = 0; jj < 2; ++jj)
    #pragma unroll
    for (int q = 0; q < 4; ++q) {
      int row = n0 + w * 16 + g * 4 + q;
      int col = jj * 16 + r16;
      if (row < NN) h2[(size_t)row * OUTC + col] = acc[jj][q];
    }
}

// ---------------- als/ald layer-1 from h1 ----------------
__global__ void k_att1(const f16* __restrict__ h1, const float* __restrict__ as1,
                       const float* __restrict__ ad1, float* __restrict__ als,
                       float* __restrict__ ald) {
  int tid = threadIdx.x, l = tid & 63;
  int n = blockIdx.x * 4 + (tid >> 6);
  int c0 = l * 4;
  f16x4 hv = *(const f16x4*)(h1 + (size_t)n * H1C + c0);
  float vs = 0.f, vd = 0.f;
  #pragma unroll
  for (int t = 0; t < 4; ++t) {
    float hf = (float)hv[t];
    vs += hf * as1[c0 + t];
    vd += hf * ad1[c0 + t];
  }
  #pragma unroll
  for (int o = 1; o < 16; o <<= 1) {
    vs += __shfl_xor(vs, o);
    vd += __shfl_xor(vd, o);
  }
  if ((l & 15) == 0) {
    int h = l >> 4;
    als[n * 4 + h] = vs;
    ald[n * 4 + h] = vd;
  }
}

// ---------------- als2/ald2 from h2 ----------------
__global__ void k_att2(const float* __restrict__ h2, const float* __restrict__ as2,
                       const float* __restrict__ ad2, float* __restrict__ als2,
                       float* __restrict__ ald2) {
  int tid = threadIdx.x;
  int n = blockIdx.x * 8 + (tid >> 5);
  int c = tid & 31;
  float v = h2[(size_t)n * OUTC + c];
  float vs = v * as2[c], vd = v * ad2[c];
  #pragma unroll
  for (int o = 1; o < 32; o <<= 1) {
    vs += __shfl_xor(vs, o, 32);
    vd += __shfl_xor(vd, o, 32);
  }
  if (c == 0) {
    als2[n] = vs;
    ald2[n] = vd;
  }
}

// ---------------- per-edge layer-1 scores (CSR order) ----------------
__global__ void k_score1(const int* __restrict__ src_sorted,
                         const int* __restrict__ dst_sorted,
                         const float* __restrict__ als, const float* __restrict__ ald,
                         float* __restrict__ scores1) {
  int p = blockIdx.x * 256 + threadIdx.x;
  if (p >= EE) return;
  int s = src_sorted[p], d = dst_sorted[p];
  const float4 a = *(const float4*)(als + s * 4);
  const float4 b = *(const float4*)(ald + d * 4);
  float4 sc;
  sc.x = leaky(a.x + b.x);
  sc.y = leaky(a.y + b.y);
  sc.z = leaky(a.z + b.z);
  sc.w = leaky(a.w + b.w);
  *(float4*)(scores1 + (size_t)p * 4) = sc;
}

// ---------------- layer-1 softmax-aggregate + bias + ELU + LN (f16 in/out) ----------------
__global__ void k_agg1(const int* __restrict__ rowst, const int* __restrict__ src_sorted,
                       const float* __restrict__ scores1, const f16* __restrict__ h1,
                       const float* __restrict__ als, const float* __restrict__ ald,
                       const float* __restrict__ b1, const float* __restrict__ g1,
                       const float* __restrict__ be1, f16* __restrict__ ln1) {
  int lane = threadIdx.x & 63;
  int n = blockIdx.x * 4 + (threadIdx.x >> 6);
  int k0 = rowst[n], k1 = rowst[n + 1];
  const float4 adv = *(const float4*)(ald + n * 4);
  const float4 asv = *(const float4*)(als + n * 4);
  float4 es;
  es.x = leaky(asv.x + adv.x); es.y = leaky(asv.y + adv.y);
  es.z = leaky(asv.z + adv.z); es.w = leaky(asv.w + adv.w);
  float m0 = es.x, m1 = es.y, m2 = es.z, m3 = es.w;
  for (int i = k0 + lane; i < k1; i += 64) {
    const float4 sc = *(const float4*)(scores1 + (size_t)i * 4);
    m0 = fmaxf(m0, sc.x); m1 = fmaxf(m1, sc.y);
    m2 = fmaxf(m2, sc.z); m3 = fmaxf(m3, sc.w);
  }
  #pragma unroll
  for (int o = 32; o >= 1; o >>= 1) {
    m0 = fmaxf(m0, __shfl_xor(m0, o));
    m1 = fmaxf(m1, __shfl_xor(m1, o));
    m2 = fmaxf(m2, __shfl_xor(m2, o));
    m3 = fmaxf(m3, __shfl_xor(m3, o));
  }
  float d0 = 0.f, d1 = 0.f, d2 = 0.f, d3 = 0.f;
  for (int i = k0 + lane; i < k1; i += 64) {
    const float4 sc = *(const float4*)(scores1 + (size_t)i * 4);
    d0 += expf(sc.x - m0); d1 += expf(sc.y - m1);
    d2 += expf(sc.z - m2); d3 += expf(sc.w - m3);
  }
  #pragma unroll
  for (int o = 32; o >= 1; o >>= 1) {
    d0 += __shfl_xor(d0, o); d1 += __shfl_xor(d1, o);
    d2 += __shfl_xor(d2, o); d3 += __shfl_xor(d3, o);
  }
  d0 += expf(es.x - m0); d1 += expf(es.y - m1);
  d2 += expf(es.z - m2); d3 += expf(es.w - m3);

  int hh = lane >> 4;
  float mh = hh == 0 ? m0 : hh == 1 ? m1 : hh == 2 ? m2 : m3;
  float dh = hh == 0 ? d0 : hh == 1 ? d1 : hh == 2 ? d2 : d3;
  float inv_dh = 1.f / dh;
  int c0 = lane * 4;
  float a_self = expf(sel4(es, hh) - mh) * inv_dh;
  f16x4 hv = *(const f16x4*)(h1 + (size_t)n * H1C + c0);
  float v0 = (float)hv[0] * a_self, v1 = (float)hv[1] * a_self;
  float v2 = (float)hv[2] * a_self, v3 = (float)hv[3] * a_self;
  for (int base = k0; base < k1; base += 64) {
    int p = base + lane;
    int sv = (p < k1) ? src_sorted[p] : 0;
    int lim = min(64, k1 - base);
    for (int j = 0; j < lim; ++j) {
      int s = __shfl(sv, j);
      const float4 sc = *(const float4*)(scores1 + (size_t)(base + j) * 4);
      float aa = expf(sel4(sc, hh) - mh) * inv_dh;
      f16x4 hg = *(const f16x4*)(h1 + (size_t)s * H1C + c0);
      v0 = fmaf((float)hg[0], aa, v0);
      v1 = fmaf((float)hg[1], aa, v1);
      v2 = fmaf((float)hg[2], aa, v2);
      v3 = fmaf((float)hg[3], aa, v3);
    }
  }
  v0 += b1[c0 + 0]; v1 += b1[c0 + 1]; v2 += b1[c0 + 2]; v3 += b1[c0 + 3];
  v0 = v0 > 0.f ? v0 : expm1f(v0);
  v1 = v1 > 0.f ? v1 : expm1f(v1);
  v2 = v2 > 0.f ? v2 : expm1f(v2);
  v3 = v3 > 0.f ? v3 : expm1f(v3);
  float s1 = v0 + v1 + v2 + v3;
  float s2 = v0 * v0 + v1 * v1 + v2 * v2 + v3 * v3;
  #pragma unroll
  for (int o = 32; o >= 1; o >>= 1) {
    s1 += __shfl_xor(s1, o);
    s2 += __shfl_xor(s2, o);
  }
  float mu = s1 * (1.f / 256.f);
  float var = s2 * (1.f / 256.f) - mu * mu;
  float sc_ = rsqrtf(var + 1e-5f);
  f16x4 o4;
  o4[0] = (f16)((v0 - mu) * sc_ * g1[c0 + 0] + be1[c0 + 0]);
  o4[1] = (f16)((v1 - mu) * sc_ * g1[c0 + 1] + be1[c0 + 1]);
  o4[2] = (f16)((v2 - mu) * sc_ * g1[c0 + 2] + be1[c0 + 2]);
  o4[3] = (f16)((v3 - mu) * sc_ * g1[c0 + 3] + be1[c0 + 3]);
  *(f16x4*)(ln1 + (size_t)n * H1C + c0) = o4;
}

// ---------------- per-edge layer-2 scores ----------------
__global__ void k_score2(const int* __restrict__ src_sorted,
                         const int* __restrict__ dst_sorted,
                         const float* __restrict__ als2, const float* __restrict__ ald2,
                         float* __restrict__ score2) {
  int p = blockIdx.x * 256 + threadIdx.x;
  if (p >= EE) return;
  score2[p] = leaky(als2[src_sorted[p]] + ald2[dst_sorted[p]]);
}

// ---------------- layer-2 softmax-aggregate + bias + LN -> out ----------------
__global__ void k_agg2(const int* __restrict__ rowst, const int* __restrict__ src_sorted,
                       const float* __restrict__ score2, const float* __restrict__ h2,
                       const float* __restrict__ als2, const float* __restrict__ ald2,
                       const float* __restrict__ b2, const float* __restrict__ g2,
                       const float* __restrict__ be2, float* __restrict__ out) {
  int lane = threadIdx.x & 63;
  int n = blockIdx.x * 4 + (threadIdx.x >> 6);
  int k0 = rowst[n], k1 = rowst[n + 1];
  float es = leaky(als2[n] + ald2[n]);
  float m = es;
  for (int i = k0 + lane; i < k1; i += 64) m = fmaxf(m, score2[i]);
  #pragma unroll
  for (int o = 32; o >= 1; o >>= 1) m = fmaxf(m, __shfl_xor(m, o));
  float d = 0.f;
  for (int i = k0 + lane; i < k1; i += 64) d += expf(score2[i] - m);
  #pragma unroll
  for (int o = 32; o >= 1; o >>= 1) d += __shfl_xor(d, o);
  d += expf(es - m);
  float inv_d = 1.f / d;
  int c = lane & 31, g = lane >> 5;
  float acc = (g == 0) ? h2[(size_t)n * OUTC + c] * (expf(es - m) * inv_d) : 0.f;
  for (int base = k0; base < k1; base += 64) {
    int p = base + lane;
    int sv = (p < k1) ? src_sorted[p] : 0;
    int lim = min(64, k1 - base);
    for (int j = g; j < lim; j += 2) {
      int s = __shfl(sv, j);
      float aa = expf(score2[base + j] - m) * inv_d;
      acc = fmaf(h2[(size_t)s * OUTC + c], aa, acc);
    }
  }
  acc += __shfl_xor(acc, 32);
  if (g == 0) {
    float v = acc + b2[c];
    float s1 = v, s2 = v * v;
    #pragma unroll
    for (int o = 16; o >= 1; o >>= 1) {
      s1 += __shfl_xor(s1, o, 32);
      s2 += __shfl_xor(s2, o, 32);
    }
    float mu = s1 * (1.f / 32.f);
    float var = s2 * (1.f / 32.f) - mu * mu;
    float sc = rsqrtf(var + 1e-5f);
    out[(size_t)n * OUTC + c] = (v - mu) * sc * g2[c] + be2[c];
  }
}

extern "C" void kernel_launch(void* const* d_in, const int* in_sizes, int n_in,
                              void* d_out, int out_size, void* d_ws, size_t ws_size,
                              hipStream_t stream) {
  const float* x   = (const float*)d_in[0];
  const int*   ei  = (const int*)d_in[1];
  const float* et  = (const float*)d_in[2];
  const float* tw  = (const float*)d_in[3];
  const float* tb  = (const float*)d_in[4];
  const float* pw  = (const float*)d_in[5];
  const float* pb  = (const float*)d_in[6];
  const float* W1  = (const float*)d_in[7];
  const float* as1 = (const float*)d_in[8];
  const float* ad1 = (const float*)d_in[9];
  const float* b1  = (const float*)d_in[10];
  const float* g1  = (const float*)d_in[11];
  const float* be1 = (const float*)d_in[12];
  const float* W2  = (const float*)d_in[13];
  const float* as2 = (const float*)d_in[14];
  const float* ad2 = (const float*)d_in[15];
  const float* b2  = (const float*)d_in[16];
  const float* g2  = (const float*)d_in[17];
  const float* be2 = (const float*)d_in[18];

  char* ws = (char*)d_ws;
  size_t off = 0;
  auto alloc = [&](size_t bytes) {
    void* p = ws + off;
    off += (bytes + 255) & ~(size_t)255;
    return p;
  };
  float* node_time = (float*)alloc((size_t)NN * TD * 4);
  f16* xin   = (f16*)alloc((size_t)NN * INC * 2);
  f16* h1    = (f16*)alloc((size_t)NN * H1C * 2);
  f16* ln1   = (f16*)alloc((size_t)NN * H1C * 2);
  float* h2  = (float*)alloc((size_t)NN * OUTC * 4);
  float* als1v = (float*)alloc((size_t)NN * 4 * 4);
  float* ald1v = (float*)alloc((size_t)NN * 4 * 4);
  float* als2v = (float*)alloc((size_t)NN * 4);
  float* ald2v = (float*)alloc((size_t)NN * 4);
  float* scores1 = (float*)alloc((size_t)EE * 4 * 4);
  float* score2  = (float*)alloc((size_t)EE * 4);
  float* et_sorted = (float*)alloc((size_t)EE * 4);
  f16* W1T = (f16*)alloc(32768 * 2);
  f16* pwT = (f16*)alloc(20480 * 2);
  f16* W2T = (f16*)alloc(8192 * 2);
  int* deg_dst = (int*)alloc((size_t)NN * 4);
  int* deg_src = (int*)alloc((size_t)NN * 4);
  int* rowst_dst = (int*)alloc((size_t)(NN + 1) * 4);
  int* rowst_src = (int*)alloc((size_t)(NN + 1) * 4);
  int* fill_dst = (int*)alloc((size_t)NN * 4);
  int* fill_src = (int*)alloc((size_t)NN * 4);
  int* src_sorted = (int*)alloc((size_t)EE * 4);
  int* dst_sorted = (int*)alloc((size_t)EE * 4);
  int* bsum_d = (int*)alloc(64 * 4);
  int* bsum_s = (int*)alloc(64 * 4);

  hipMemsetAsync(deg_dst, 0, (size_t)NN * 4, stream);
  hipMemsetAsync(deg_src, 0, (size_t)NN * 4, stream);

  const int NB = (NN + 1023) / 1024;  // 49
  const int NT64 = (NN + 63) / 64;    // 782
  k_deg<<<(EE + 255) / 256, 256, 0, stream>>>(ei, deg_dst, deg_src);
  k_prep<<<240, 256, 0, stream>>>(W1, pw, W2, W1T, pwT, W2T);
  k_scan1<<<NB, 1024, 0, stream>>>(deg_dst, rowst_dst, bsum_d);
  k_scan1<<<NB, 1024, 0, stream>>>(deg_src, rowst_src, bsum_s);
  k_scan2<<<1, 64, 0, stream>>>(bsum_d, NB);
  k_scan2<<<1, 64, 0, stream>>>(bsum_s, NB);
  k_scan3<<<(NN + 255) / 256, 256, 0, stream>>>(rowst_dst, bsum_d, fill_dst);
  k_scan3<<<(NN + 255) / 256, 256, 0, stream>>>(rowst_src, bsum_s, fill_src);
  k_scatter<<<(EE + 255) / 256, 256, 0, stream>>>(ei, et, fill_dst, fill_src,
                                                  src_sorted, dst_sorted, et_sorted);
  k_time_agg<<<NN / 4, 256, 0, stream>>>(rowst_src, et_sorted, tw, tb, node_time);
  k_projg<<<NT64, 256, 0, stream>>>(x, node_time, pwT, pb, xin);
  k_h1g<<<NT64, 256, 0, stream>>>(xin, W1T, h1);
  k_att1<<<NN / 4, 256, 0, stream>>>(h1, as1, ad1, als1v, ald1v);
  k_score1<<<(EE + 255) / 256, 256, 0, stream>>>(src_sorted, dst_sorted, als1v, ald1v, scores1);
  k_agg1<<<NN / 4, 256, 0, stream>>>(rowst_dst, src_sorted, scores1, h1, als1v, ald1v,
                                     b1, g1, be1, ln1);
  k_h2g<<<NT64, 256, 0, stream>>>(ln1, W2T, h2);
  k_att2<<<NN / 8, 256, 0, stream>>>(h2, as2, ad2, als2v, ald2v);
  k_score2<<<(EE + 255) / 256, 256, 0, stream>>>(src_sorted, dst_sorted, als2v, ald2v, score2);
  k_agg2<<<NN / 4, 256, 0, stream>>>(rowst_dst, src_sorted, score2, h2, als2v, ald2v,
                                     b2, g2, be2, (float*)d_out);
}

// Round 4
// 271.119 us; speedup vs baseline: 1.8349x; 1.1474x over previous
//
#include <hip/hip_runtime.h>
#include <math.h>

#define NN 50000
#define EE 400000
#define INC 128
#define TD 16
#define H1C 256   // HEADS*HID
#define OUTC 32
#define NEG 0.2f

typedef _Float16 f16;
typedef __attribute__((ext_vector_type(8))) _Float16 f16x8;
typedef __attribute__((ext_vector_type(4))) _Float16 f16x4;
typedef __attribute__((ext_vector_type(4))) float f32x4;

__device__ __forceinline__ float leaky(float x) { return x > 0.f ? x : NEG * x; }

// ---------------- fused degree count + weight prep ----------------
__global__ void k_deg_prep(const int* __restrict__ ei, int* __restrict__ deg_dst,
                           int* __restrict__ deg_src, const float* __restrict__ W1,
                           const float* __restrict__ pw, const float* __restrict__ W2,
                           f16* __restrict__ W1T, f16* __restrict__ pwT,
                           f16* __restrict__ W2T) {
  int gid = blockIdx.x * 256 + threadIdx.x;
  if (gid < EE) {
    atomicAdd(&deg_dst[ei[EE + gid]], 1);
    atomicAdd(&deg_src[ei[gid]], 1);
    return;
  }
  int idx = gid - EE;
  if (idx < 32768) {
    int c = idx >> 7, k = idx & 127;
    W1T[idx] = (f16)W1[k * 256 + c];
  } else if (idx < 53248) {
    int i2 = idx - 32768;
    int c = i2 / 160, kp = i2 - c * 160;
    pwT[i2] = (f16)(kp < 144 ? pw[kp * 128 + c] : 0.f);
  } else if (idx < 61440) {
    int i3 = idx - 53248;
    int c = i3 >> 8, k = i3 & 255;
    W2T[i3] = (f16)W2[k * 32 + c];
  }
}

// ---------------- exclusive scan pipeline (y=0: dst, y=1: src) ----------------
__global__ void k_scan1(const int* __restrict__ deg_d, const int* __restrict__ deg_s,
                        int* __restrict__ rowst_d, int* __restrict__ rowst_s,
                        int* __restrict__ bs_d, int* __restrict__ bs_s) {
  const int* deg = blockIdx.y ? deg_s : deg_d;
  int* rowst = blockIdx.y ? rowst_s : rowst_d;
  int* bsum = blockIdx.y ? bs_s : bs_d;
  __shared__ int sh[1024];
  int tid = threadIdx.x;
  int i = blockIdx.x * 1024 + tid;
  int v = (i < NN) ? deg[i] : 0;
  sh[tid] = v;
  __syncthreads();
  for (int off = 1; off < 1024; off <<= 1) {
    int t = (tid >= off) ? sh[tid - off] : 0;
    __syncthreads();
    sh[tid] += t;
    __syncthreads();
  }
  if (i < NN) rowst[i] = sh[tid] - v;
  if (tid == 1023) bsum[blockIdx.x] = sh[1023];
}

__global__ void k_scan2(int* __restrict__ bs_d, int* __restrict__ bs_s, int nb) {
  int tid = threadIdx.x;  // 128 threads, 2 waves
  int lane = tid & 63;
  int* bsum = (tid >> 6) ? bs_s : bs_d;
  int v = (lane < nb) ? bsum[lane] : 0;
  int incl = v;
  #pragma unroll
  for (int off = 1; off < 64; off <<= 1) {
    int t = __shfl_up(incl, off);
    if (lane >= off) incl += t;
  }
  if (lane < nb) bsum[lane] = incl - v;
}

__global__ void k_scan3(int* __restrict__ rowst_d, int* __restrict__ rowst_s,
                        const int* __restrict__ bs_d, const int* __restrict__ bs_s,
                        int* __restrict__ fill_d, int* __restrict__ fill_s) {
  int* rowst = blockIdx.y ? rowst_s : rowst_d;
  const int* bsum = blockIdx.y ? bs_s : bs_d;
  int* fill = blockIdx.y ? fill_s : fill_d;
  int i = blockIdx.x * 256 + threadIdx.x;
  if (i < NN) {
    int r = rowst[i] + bsum[i >> 10];
    rowst[i] = r;
    fill[i] = r;
  }
  if (i == 0) rowst[NN] = EE;
}

__global__ void k_scatter(const int* __restrict__ ei, const float* __restrict__ et,
                          int* __restrict__ fill_dst, int* __restrict__ fill_src,
                          int* __restrict__ src_sorted, int* __restrict__ dst_sorted,
                          float* __restrict__ et_sorted) {
  int e = blockIdx.x * 256 + threadIdx.x;
  if (e >= EE) return;
  int s = ei[e], d = ei[EE + e];
  int p1 = atomicAdd(&fill_dst[d], 1);
  src_sorted[p1] = s;
  dst_sorted[p1] = d;
  int p2 = atomicAdd(&fill_src[s], 1);
  et_sorted[p2] = et[e];
}

// ---------------- time encoding, segmented mean over src-CSR ----------------
__global__ void k_time_agg(const int* __restrict__ rowst_src,
                           const float* __restrict__ et_sorted,
                           const float* __restrict__ tw, const float* __restrict__ tb,
                           float* __restrict__ node_time) {
  int lane = threadIdx.x & 63;
  int n = blockIdx.x * 4 + (threadIdx.x >> 6);
  int k0 = rowst_src[n], k1 = rowst_src[n + 1];
  int k = lane & 15, g = lane >> 4;
  float w = tw[k], b = tb[k];
  bool isc = (k & 1);
  float v = 0.f;
  for (int i = k0 + g; i < k1; i += 4) {
    float tp = et_sorted[i] * w + b;
    v += isc ? __cosf(tp) : __sinf(tp);
  }
  v += __shfl_xor(v, 16);
  v += __shfl_xor(v, 32);
  if (lane < 16) node_time[n * TD + k] = v / (float)(k1 - k0 + 1);
}

// ---------------- MFMA proj: xin = [x|node_time] @ pw + pb  (f16 out) ----------------
__global__ __launch_bounds__(256) void k_projg(const float* __restrict__ x,
                                               const float* __restrict__ node_time,
                                               const f16* __restrict__ pwT,
                                               const float* __restrict__ pb,
                                               f16* __restrict__ xin) {
  __shared__ f16 A[64 * 168];  // 64 rows x 160 k (pad 8)
  int tid = threadIdx.x, l = tid & 63, w = tid >> 6;
  int n0 = blockIdx.x * 64;
  for (int idx = tid; idx < 64 * 160; idx += 256) {
    int r = idx / 160, c = idx - r * 160;
    int n = n0 + r;
    float v = 0.f;
    if (n < NN) v = (c < 128) ? x[(size_t)n * INC + c]
                              : (c < 144 ? node_time[n * TD + (c - 128)] : 0.f);
    A[r * 168 + c] = (f16)v;
  }
  int r16 = l & 15, g = l >> 4;
  f16x8 breg[2][5];
  #pragma unroll
  for (int jj = 0; jj < 2; ++jj) {
    int col = w * 32 + jj * 16 + r16;
    #pragma unroll
    for (int kk = 0; kk < 5; ++kk)
      breg[jj][kk] = *(const f16x8*)(pwT + col * 160 + kk * 32 + g * 8);
  }
  f32x4 acc[4][2];
  #pragma unroll
  for (int i = 0; i < 4; ++i)
    #pragma unroll
    for (int jj = 0; jj < 2; ++jj) acc[i][jj] = (f32x4){0.f, 0.f, 0.f, 0.f};
  __syncthreads();
  #pragma unroll
  for (int kk = 0; kk < 5; ++kk) {
    #pragma unroll
    for (int i = 0; i < 4; ++i) {
      f16x8 a = *(const f16x8*)(A + (i * 16 + r16) * 168 + kk * 32 + g * 8);
      acc[i][0] = __builtin_amdgcn_mfma_f32_16x16x32_f16(a, breg[0][kk], acc[i][0], 0, 0, 0);
      acc[i][1] = __builtin_amdgcn_mfma_f32_16x16x32_f16(a, breg[1][kk], acc[i][1], 0, 0, 0);
    }
  }
  #pragma unroll
  for (int i = 0; i < 4; ++i)
    #pragma unroll
    for (int jj = 0; jj < 2; ++jj) {
      int col = w * 32 + jj * 16 + r16;
      float bj = pb[col];
      #pragma unroll
      for (int q = 0; q < 4; ++q) {
        int row = n0 + i * 16 + g * 4 + q;
        if (row < NN) xin[(size_t)row * INC + col] = (f16)(acc[i][jj][q] + bj);
      }
    }
}

// ---------------- MFMA h1 = xin @ W1 (f16 out) + fused att1 ----------------
__global__ __launch_bounds__(256) void k_h1g(const f16* __restrict__ xin,
                                             const f16* __restrict__ W1T,
                                             const float* __restrict__ as1,
                                             const float* __restrict__ ad1,
                                             f16* __restrict__ h1,
                                             float* __restrict__ als,
                                             float* __restrict__ ald) {
  __shared__ f16 A[64 * 136];  // 64 x 128 (pad 8)
  int tid = threadIdx.x, l = tid & 63, w = tid >> 6;
  int n0 = blockIdx.x * 64;
  f16x8 zero = {};
  for (int ci = tid; ci < 1024; ci += 256) {
    int r = ci >> 4, c8 = (ci & 15) * 8;
    int n = n0 + r;
    f16x8 v = (n < NN) ? *(const f16x8*)(xin + (size_t)n * INC + c8) : zero;
    *(f16x8*)(A + r * 136 + c8) = v;
  }
  int r16 = l & 15, g = l >> 4;
  f16x8 breg[4][4];
  #pragma unroll
  for (int jj = 0; jj < 4; ++jj) {
    int col = w * 64 + jj * 16 + r16;
    #pragma unroll
    for (int kk = 0; kk < 4; ++kk)
      breg[jj][kk] = *(const f16x8*)(W1T + col * 128 + kk * 32 + g * 8);
  }
  f32x4 acc[4][4];
  #pragma unroll
  for (int i = 0; i < 4; ++i)
    #pragma unroll
    for (int jj = 0; jj < 4; ++jj) acc[i][jj] = (f32x4){0.f, 0.f, 0.f, 0.f};
  __syncthreads();
  #pragma unroll
  for (int kk = 0; kk < 4; ++kk)
    #pragma unroll
    for (int i = 0; i < 4; ++i) {
      f16x8 a = *(const f16x8*)(A + (i * 16 + r16) * 136 + kk * 32 + g * 8);
      #pragma unroll
      for (int jj = 0; jj < 4; ++jj)
        acc[i][jj] = __builtin_amdgcn_mfma_f32_16x16x32_f16(a, breg[jj][kk], acc[i][jj], 0, 0, 0);
    }
  #pragma unroll
  for (int i = 0; i < 4; ++i)
    #pragma unroll
    for (int jj = 0; jj < 4; ++jj) {
      int col = w * 64 + jj * 16 + r16;
      #pragma unroll
      for (int q = 0; q < 4; ++q) {
        int row = n0 + i * 16 + g * 4 + q;
        if (row < NN) h1[(size_t)row * H1C + col] = (f16)acc[i][jj][q];
      }
    }
  // fused att1: head w (wave w owns cols w*64..w*64+63)
  float asc[4], adc[4];
  #pragma unroll
  for (int jj = 0; jj < 4; ++jj) {
    int col = w * 64 + jj * 16 + r16;
    asc[jj] = as1[col];
    adc[jj] = ad1[col];
  }
  #pragma unroll
  for (int i = 0; i < 4; ++i)
    #pragma unroll
    for (int q = 0; q < 4; ++q) {
      float ps = 0.f, pd = 0.f;
      #pragma unroll
      for (int jj = 0; jj < 4; ++jj) {
        ps = fmaf(acc[i][jj][q], asc[jj], ps);
        pd = fmaf(acc[i][jj][q], adc[jj], pd);
      }
      #pragma unroll
      for (int o = 1; o < 16; o <<= 1) {
        ps += __shfl_xor(ps, o);
        pd += __shfl_xor(pd, o);
      }
      int row = n0 + i * 16 + g * 4 + q;
      if (r16 == 0 && row < NN) {
        als[row * 4 + w] = ps;
        ald[row * 4 + w] = pd;
      }
    }
}

// ---------------- MFMA h2 = ln1 @ W2 (f32 out) + fused att2 ----------------
__global__ __launch_bounds__(256) void k_h2g(const f16* __restrict__ ln1,
                                             const f16* __restrict__ W2T,
                                             const float* __restrict__ as2,
                                             const float* __restrict__ ad2,
                                             float* __restrict__ h2,
                                             float* __restrict__ als2,
                                             float* __restrict__ ald2) {
  __shared__ f16 A[64 * 264];  // 64 x 256 (pad 8)
  int tid = threadIdx.x, l = tid & 63, w = tid >> 6;
  int n0 = blockIdx.x * 64;
  f16x8 zero = {};
  for (int ci = tid; ci < 2048; ci += 256) {
    int r = ci >> 5, c8 = (ci & 31) * 8;
    int n = n0 + r;
    f16x8 v = (n < NN) ? *(const f16x8*)(ln1 + (size_t)n * H1C + c8) : zero;
    *(f16x8*)(A + r * 264 + c8) = v;
  }
  int r16 = l & 15, g = l >> 4;
  f16x8 breg[2][8];
  #pragma unroll
  for (int jj = 0; jj < 2; ++jj) {
    int col = jj * 16 + r16;
    #pragma unroll
    for (int kk = 0; kk < 8; ++kk)
      breg[jj][kk] = *(const f16x8*)(W2T + col * 256 + kk * 32 + g * 8);
  }
  f32x4 acc[2];
  acc[0] = (f32x4){0.f, 0.f, 0.f, 0.f};
  acc[1] = (f32x4){0.f, 0.f, 0.f, 0.f};
  __syncthreads();
  #pragma unroll
  for (int kk = 0; kk < 8; ++kk) {
    f16x8 a = *(const f16x8*)(A + (w * 16 + r16) * 264 + kk * 32 + g * 8);
    acc[0] = __builtin_amdgcn_mfma_f32_16x16x32_f16(a, breg[0][kk], acc[0], 0, 0, 0);
    acc[1] = __builtin_amdgcn_mfma_f32_16x16x32_f16(a, breg[1][kk], acc[1], 0, 0, 0);
  }
  #pragma unroll
  for (int jj = 0; jj < 2; ++jj)
    #pragma unroll
    for (int q = 0; q < 4; ++q) {
      int row = n0 + w * 16 + g * 4 + q;
      int col = jj * 16 + r16;
      if (row < NN) h2[(size_t)row * OUTC + col] = acc[jj][q];
    }
  // fused att2 (single head; 16 lanes (r16) hold a full 32-ch row)
  float as_0 = as2[r16], as_1 = as2[16 + r16];
  float ad_0 = ad2[r16], ad_1 = ad2[16 + r16];
  #pragma unroll
  for (int q = 0; q < 4; ++q) {
    float ps = acc[0][q] * as_0 + acc[1][q] * as_1;
    float pd = acc[0][q] * ad_0 + acc[1][q] * ad_1;
    #pragma unroll
    for (int o = 1; o < 16; o <<= 1) {
      ps += __shfl_xor(ps, o);
      pd += __shfl_xor(pd, o);
    }
    int row = n0 + w * 16 + g * 4 + q;
    if (r16 == 0 && row < NN) {
      als2[row] = ps;
      ald2[row] = pd;
    }
  }
}

// ---------------- per-edge layer-1 exp(score) ----------------
__global__ void k_score1(const int* __restrict__ src_sorted,
                         const int* __restrict__ dst_sorted,
                         const float* __restrict__ als, const float* __restrict__ ald,
                         float* __restrict__ ex1) {
  int p = blockIdx.x * 256 + threadIdx.x;
  if (p >= EE) return;
  int s = src_sorted[p], d = dst_sorted[p];
  const float4 a = *(const float4*)(als + s * 4);
  const float4 b = *(const float4*)(ald + d * 4);
  float4 sc;
  sc.x = __expf(leaky(a.x + b.x));
  sc.y = __expf(leaky(a.y + b.y));
  sc.z = __expf(leaky(a.z + b.z));
  sc.w = __expf(leaky(a.w + b.w));
  *(float4*)(ex1 + (size_t)p * 4) = sc;
}

// ---------------- layer-1 aggregate + bias + ELU + LN (no max-shift; scores O(1)) ----------------
__global__ void k_agg1(const int* __restrict__ rowst, const int* __restrict__ src_sorted,
                       const float* __restrict__ ex1, const f16* __restrict__ h1,
                       const float* __restrict__ als, const float* __restrict__ ald,
                       const float* __restrict__ b1, const float* __restrict__ g1,
                       const float* __restrict__ be1, f16* __restrict__ ln1) {
  int lane = threadIdx.x & 63;
  int n = blockIdx.x * 4 + (threadIdx.x >> 6);
  int k0 = rowst[n], k1 = rowst[n + 1];
  const float4 adv = *(const float4*)(ald + n * 4);
  const float4 asv = *(const float4*)(als + n * 4);
  float se0 = __expf(leaky(asv.x + adv.x));
  float se1 = __expf(leaky(asv.y + adv.y));
  float se2 = __expf(leaky(asv.z + adv.z));
  float se3 = __expf(leaky(asv.w + adv.w));
  // denominator (coalesced)
  float d0 = 0.f, d1 = 0.f, d2 = 0.f, d3 = 0.f;
  for (int i = k0 + lane; i < k1; i += 64) {
    const float4 e = *(const float4*)(ex1 + (size_t)i * 4);
    d0 += e.x; d1 += e.y; d2 += e.z; d3 += e.w;
  }
  #pragma unroll
  for (int o = 32; o >= 1; o >>= 1) {
    d0 += __shfl_xor(d0, o); d1 += __shfl_xor(d1, o);
    d2 += __shfl_xor(d2, o); d3 += __shfl_xor(d3, o);
  }
  d0 += se0; d1 += se1; d2 += se2; d3 += se3;
  int hh = lane >> 4;
  float invd = 1.f / (hh == 0 ? d0 : hh == 1 ? d1 : hh == 2 ? d2 : d3);
  float seh = hh == 0 ? se0 : hh == 1 ? se1 : hh == 2 ? se2 : se3;
  int c0 = lane * 4;
  f16x4 hv = *(const f16x4*)(h1 + (size_t)n * H1C + c0);
  float v0 = (float)hv[0] * seh, v1 = (float)hv[1] * seh;
  float v2 = (float)hv[2] * seh, v3 = (float)hv[3] * seh;
  for (int base = k0; base < k1; base += 64) {
    int p = base + lane;
    int sv = (p < k1) ? src_sorted[p] : 0;
    int lim = min(64, k1 - base);
    for (int j = 0; j < lim; ++j) {
      int s = __shfl(sv, j);
      float aa = ex1[(size_t)(base + j) * 4 + hh];  // L1-broadcast
      f16x4 hg = *(const f16x4*)(h1 + (size_t)s * H1C + c0);
      v0 = fmaf((float)hg[0], aa, v0);
      v1 = fmaf((float)hg[1], aa, v1);
      v2 = fmaf((float)hg[2], aa, v2);
      v3 = fmaf((float)hg[3], aa, v3);
    }
  }
  v0 = fmaf(v0, invd, b1[c0 + 0]);
  v1 = fmaf(v1, invd, b1[c0 + 1]);
  v2 = fmaf(v2, invd, b1[c0 + 2]);
  v3 = fmaf(v3, invd, b1[c0 + 3]);
  v0 = v0 > 0.f ? v0 : expm1f(v0);
  v1 = v1 > 0.f ? v1 : expm1f(v1);
  v2 = v2 > 0.f ? v2 : expm1f(v2);
  v3 = v3 > 0.f ? v3 : expm1f(v3);
  float s1 = v0 + v1 + v2 + v3;
  float s2 = v0 * v0 + v1 * v1 + v2 * v2 + v3 * v3;
  #pragma unroll
  for (int o = 32; o >= 1; o >>= 1) {
    s1 += __shfl_xor(s1, o);
    s2 += __shfl_xor(s2, o);
  }
  float mu = s1 * (1.f / 256.f);
  float var = s2 * (1.f / 256.f) - mu * mu;
  float sc_ = rsqrtf(var + 1e-5f);
  f16x4 o4;
  o4[0] = (f16)((v0 - mu) * sc_ * g1[c0 + 0] + be1[c0 + 0]);
  o4[1] = (f16)((v1 - mu) * sc_ * g1[c0 + 1] + be1[c0 + 1]);
  o4[2] = (f16)((v2 - mu) * sc_ * g1[c0 + 2] + be1[c0 + 2]);
  o4[3] = (f16)((v3 - mu) * sc_ * g1[c0 + 3] + be1[c0 + 3]);
  *(f16x4*)(ln1 + (size_t)n * H1C + c0) = o4;
}

// ---------------- per-edge layer-2 exp(score) ----------------
__global__ void k_score2(const int* __restrict__ src_sorted,
                         const int* __restrict__ dst_sorted,
                         const float* __restrict__ als2, const float* __restrict__ ald2,
                         float* __restrict__ ex2) {
  int p = blockIdx.x * 256 + threadIdx.x;
  if (p >= EE) return;
  ex2[p] = __expf(leaky(als2[src_sorted[p]] + ald2[dst_sorted[p]]));
}

// ---------------- layer-2 aggregate + bias + LN -> out ----------------
__global__ void k_agg2(const int* __restrict__ rowst, const int* __restrict__ src_sorted,
                       const float* __restrict__ ex2, const float* __restrict__ h2,
                       const float* __restrict__ als2, const float* __restrict__ ald2,
                       const float* __restrict__ b2, const float* __restrict__ g2,
                       const float* __restrict__ be2, float* __restrict__ out) {
  int lane = threadIdx.x & 63;
  int n = blockIdx.x * 4 + (threadIdx.x >> 6);
  int k0 = rowst[n], k1 = rowst[n + 1];
  float se = __expf(leaky(als2[n] + ald2[n]));
  float d = 0.f;
  for (int i = k0 + lane; i < k1; i += 64) d += ex2[i];
  #pragma unroll
  for (int o = 32; o >= 1; o >>= 1) d += __shfl_xor(d, o);
  d += se;
  float invd = 1.f / d;
  int c = lane & 31, g = lane >> 5;
  float acc = (g == 0) ? h2[(size_t)n * OUTC + c] * se : 0.f;
  for (int base = k0; base < k1; base += 64) {
    int p = base + lane;
    int sv = (p < k1) ? src_sorted[p] : 0;
    float ev = (p < k1) ? ex2[p] : 0.f;
    int lim = min(64, k1 - base);
    for (int j = 0; j < lim; j += 2) {
      int jj = j + g;
      if (jj < lim) {
        int s = __shfl(sv, jj);
        float aa = __shfl(ev, jj);
        acc = fmaf(h2[(size_t)s * OUTC + c], aa, acc);
      }
    }
  }
  acc += __shfl_xor(acc, 32);
  if (g == 0) {
    float v = fmaf(acc, invd, b2[c]);
    float s1 = v, s2 = v * v;
    #pragma unroll
    for (int o = 16; o >= 1; o >>= 1) {
      s1 += __shfl_xor(s1, o, 32);
      s2 += __shfl_xor(s2, o, 32);
    }
    float mu = s1 * (1.f / 32.f);
    float var = s2 * (1.f / 32.f) - mu * mu;
    float sc = rsqrtf(var + 1e-5f);
    out[(size_t)n * OUTC + c] = (v - mu) * sc * g2[c] + be2[c];
  }
}

extern "C" void kernel_launch(void* const* d_in, const int* in_sizes, int n_in,
                              void* d_out, int out_size, void* d_ws, size_t ws_size,
                              hipStream_t stream) {
  const float* x   = (const float*)d_in[0];
  const int*   ei  = (const int*)d_in[1];
  const float* et  = (const float*)d_in[2];
  const float* tw  = (const float*)d_in[3];
  const float* tb  = (const float*)d_in[4];
  const float* pw  = (const float*)d_in[5];
  const float* pb  = (const float*)d_in[6];
  const float* W1  = (const float*)d_in[7];
  const float* as1 = (const float*)d_in[8];
  const float* ad1 = (const float*)d_in[9];
  const float* b1  = (const float*)d_in[10];
  const float* g1  = (const float*)d_in[11];
  const float* be1 = (const float*)d_in[12];
  const float* W2  = (const float*)d_in[13];
  const float* as2 = (const float*)d_in[14];
  const float* ad2 = (const float*)d_in[15];
  const float* b2  = (const float*)d_in[16];
  const float* g2  = (const float*)d_in[17];
  const float* be2 = (const float*)d_in[18];

  char* ws = (char*)d_ws;
  size_t off = 0;
  auto alloc = [&](size_t bytes) {
    void* p = ws + off;
    off += (bytes + 255) & ~(size_t)255;
    return p;
  };
  float* node_time = (float*)alloc((size_t)NN * TD * 4);
  f16* xin   = (f16*)alloc((size_t)NN * INC * 2);
  f16* h1    = (f16*)alloc((size_t)NN * H1C * 2);
  f16* ln1   = (f16*)alloc((size_t)NN * H1C * 2);
  float* h2  = (float*)alloc((size_t)NN * OUTC * 4);
  float* als1v = (float*)alloc((size_t)NN * 4 * 4);
  float* ald1v = (float*)alloc((size_t)NN * 4 * 4);
  float* als2v = (float*)alloc((size_t)NN * 4);
  float* ald2v = (float*)alloc((size_t)NN * 4);
  float* ex1 = (float*)alloc((size_t)EE * 4 * 4);
  float* ex2 = (float*)alloc((size_t)EE * 4);
  float* et_sorted = (float*)alloc((size_t)EE * 4);
  f16* W1T = (f16*)alloc(32768 * 2);
  f16* pwT = (f16*)alloc(20480 * 2);
  f16* W2T = (f16*)alloc(8192 * 2);
  int* deg2 = (int*)alloc((size_t)NN * 2 * 4);  // deg_dst | deg_src contiguous
  int* deg_dst = deg2;
  int* deg_src = deg2 + NN;
  int* rowst_dst = (int*)alloc((size_t)(NN + 1) * 4);
  int* rowst_src = (int*)alloc((size_t)(NN + 1) * 4);
  int* fill_dst = (int*)alloc((size_t)NN * 4);
  int* fill_src = (int*)alloc((size_t)NN * 4);
  int* src_sorted = (int*)alloc((size_t)EE * 4);
  int* dst_sorted = (int*)alloc((size_t)EE * 4);
  int* bsum_d = (int*)alloc(64 * 4);
  int* bsum_s = (int*)alloc(64 * 4);

  hipMemsetAsync(deg2, 0, (size_t)NN * 2 * 4, stream);

  const int NB = (NN + 1023) / 1024;  // 49
  const int NT64 = (NN + 63) / 64;    // 782
  k_deg_prep<<<(EE + 61440 + 255) / 256, 256, 0, stream>>>(ei, deg_dst, deg_src, W1, pw,
                                                           W2, W1T, pwT, W2T);
  k_scan1<<<dim3(NB, 2), 1024, 0, stream>>>(deg_dst, deg_src, rowst_dst, rowst_src,
                                            bsum_d, bsum_s);
  k_scan2<<<1, 128, 0, stream>>>(bsum_d, bsum_s, NB);
  k_scan3<<<dim3((NN + 255) / 256, 2), 256, 0, stream>>>(rowst_dst, rowst_src, bsum_d,
                                                         bsum_s, fill_dst, fill_src);
  k_scatter<<<(EE + 255) / 256, 256, 0, stream>>>(ei, et, fill_dst, fill_src,
                                                  src_sorted, dst_sorted, et_sorted);
  k_time_agg<<<NN / 4, 256, 0, stream>>>(rowst_src, et_sorted, tw, tb, node_time);
  k_projg<<<NT64, 256, 0, stream>>>(x, node_time, pwT, pb, xin);
  k_h1g<<<NT64, 256, 0, stream>>>(xin, W1T, as1, ad1, h1, als1v, ald1v);
  k_score1<<<(EE + 255) / 256, 256, 0, stream>>>(src_sorted, dst_sorted, als1v, ald1v, ex1);
  k_agg1<<<NN / 4, 256, 0, stream>>>(rowst_dst, src_sorted, ex1, h1, als1v, ald1v,
                                     b1, g1, be1, ln1);
  k_h2g<<<NT64, 256, 0, stream>>>(ln1, W2T, as2, ad2, h2, als2v, ald2v);
  k_score2<<<(EE + 255) / 256, 256, 0, stream>>>(src_sorted, dst_sorted, als2v, ald2v, ex2);
  k_agg2<<<NN / 4, 256, 0, stream>>>(rowst_dst, src_sorted, ex2, h2, als2v, ald2v,
                                     b2, g2, be2, (float*)d_out);
}

// Round 5
// 239.349 us; speedup vs baseline: 2.0785x; 1.1327x over previous
//
#include <hip/hip_runtime.h>
#include <math.h>

#define NN 50000
#define EE 400000
#define INC 128
#define TD 16
#define H1C 256   // HEADS*HID
#define OUTC 32
#define NEG 0.2f

typedef _Float16 f16;
typedef __attribute__((ext_vector_type(8))) _Float16 f16x8;
typedef __attribute__((ext_vector_type(4))) _Float16 f16x4;
typedef __attribute__((ext_vector_type(4))) float f32x4;

__device__ __forceinline__ float leaky(float x) { return x > 0.f ? x : NEG * x; }

// ---------------- fused degree count + weight prep ----------------
__global__ void k_deg_prep(const int* __restrict__ ei, int* __restrict__ deg_dst,
                           int* __restrict__ deg_src, const float* __restrict__ W1,
                           const float* __restrict__ pw, const float* __restrict__ W2,
                           f16* __restrict__ W1T, f16* __restrict__ pwT,
                           f16* __restrict__ W2T) {
  int gid = blockIdx.x * 256 + threadIdx.x;
  if (gid < EE) {
    atomicAdd(&deg_dst[ei[EE + gid]], 1);
    atomicAdd(&deg_src[ei[gid]], 1);
    return;
  }
  int idx = gid - EE;
  if (idx < 32768) {
    int c = idx >> 7, k = idx & 127;
    W1T[idx] = (f16)W1[k * 256 + c];
  } else if (idx < 53248) {
    int i2 = idx - 32768;
    int c = i2 / 160, kp = i2 - c * 160;
    pwT[i2] = (f16)(kp < 144 ? pw[kp * 128 + c] : 0.f);
  } else if (idx < 61440) {
    int i3 = idx - 53248;
    int c = i3 >> 8, k = i3 & 255;
    W2T[i3] = (f16)W2[k * 32 + c];
  }
}

// ---------------- block scan (y=0: dst, y=1: src) ----------------
__global__ void k_scan1(const int* __restrict__ deg_d, const int* __restrict__ deg_s,
                        int* __restrict__ rowst_d, int* __restrict__ rowst_s,
                        int* __restrict__ bs_d, int* __restrict__ bs_s) {
  const int* deg = blockIdx.y ? deg_s : deg_d;
  int* rowst = blockIdx.y ? rowst_s : rowst_d;
  int* bsum = blockIdx.y ? bs_s : bs_d;
  __shared__ int sh[1024];
  int tid = threadIdx.x;
  int i = blockIdx.x * 1024 + tid;
  int v = (i < NN) ? deg[i] : 0;
  sh[tid] = v;
  __syncthreads();
  for (int off = 1; off < 1024; off <<= 1) {
    int t = (tid >= off) ? sh[tid - off] : 0;
    __syncthreads();
    sh[tid] += t;
    __syncthreads();
  }
  if (i < NN) rowst[i] = sh[tid] - v;
  if (tid == 1023) bsum[blockIdx.x] = sh[1023];
}

// scan3 with inlined block-offset reduce (replaces old scan2+scan3)
__global__ void k_scan3(int* __restrict__ rowst_d, int* __restrict__ rowst_s,
                        const int* __restrict__ bs_d, const int* __restrict__ bs_s,
                        int* __restrict__ fill_d, int* __restrict__ fill_s) {
  int* rowst = blockIdx.y ? rowst_s : rowst_d;
  const int* bsum = blockIdx.y ? bs_s : bs_d;
  int* fill = blockIdx.y ? fill_s : fill_d;
  __shared__ int off_sh;
  int tid = threadIdx.x;
  int chunk = blockIdx.x >> 2;  // 256-node blocks -> 1024-node scan1 chunks
  if (tid < 64) {
    int v = (tid < chunk) ? bsum[tid] : 0;  // chunk <= 48 < 64
    #pragma unroll
    for (int o = 32; o >= 1; o >>= 1) v += __shfl_xor(v, o);
    if (tid == 0) off_sh = v;
  }
  __syncthreads();
  int i = blockIdx.x * 256 + tid;
  if (i < NN) {
    int r = rowst[i] + off_sh;
    rowst[i] = r;
    fill[i] = r;
  }
  if (i == 0) rowst[NN] = EE;
}

__global__ void k_scatter(const int* __restrict__ ei, const float* __restrict__ et,
                          int* __restrict__ fill_dst, int* __restrict__ fill_src,
                          int* __restrict__ src_sorted, float* __restrict__ et_sorted) {
  int e = blockIdx.x * 256 + threadIdx.x;
  if (e >= EE) return;
  int s = ei[e], d = ei[EE + e];
  int p1 = atomicAdd(&fill_dst[d], 1);
  src_sorted[p1] = s;
  int p2 = atomicAdd(&fill_src[s], 1);
  et_sorted[p2] = et[e];
}

// ---------------- time encoding, segmented mean over src-CSR ----------------
__global__ void k_time_agg(const int* __restrict__ rowst_src,
                           const float* __restrict__ et_sorted,
                           const float* __restrict__ tw, const float* __restrict__ tb,
                           float* __restrict__ node_time) {
  int lane = threadIdx.x & 63;
  int n = blockIdx.x * 4 + (threadIdx.x >> 6);
  int k0 = rowst_src[n], k1 = rowst_src[n + 1];
  int k = lane & 15, g = lane >> 4;
  float w = tw[k], b = tb[k];
  bool isc = (k & 1);
  float v = 0.f;
  for (int i = k0 + g; i < k1; i += 4) {
    float tp = et_sorted[i] * w + b;
    v += isc ? __cosf(tp) : __sinf(tp);
  }
  v += __shfl_xor(v, 16);
  v += __shfl_xor(v, 32);
  if (lane < 16) node_time[n * TD + k] = v / (float)(k1 - k0 + 1);
}

// ---------------- MFMA proj: xin = [x|node_time] @ pw + pb  (f16 out) ----------------
__global__ __launch_bounds__(256) void k_projg(const float* __restrict__ x,
                                               const float* __restrict__ node_time,
                                               const f16* __restrict__ pwT,
                                               const float* __restrict__ pb,
                                               f16* __restrict__ xin) {
  __shared__ f16 A[64 * 168];  // 64 rows x 160 k (pad 8)
  int tid = threadIdx.x, l = tid & 63, w = tid >> 6;
  int n0 = blockIdx.x * 64;
  for (int idx = tid; idx < 64 * 160; idx += 256) {
    int r = idx / 160, c = idx - r * 160;
    int n = n0 + r;
    float v = 0.f;
    if (n < NN) v = (c < 128) ? x[(size_t)n * INC + c]
                              : (c < 144 ? node_time[n * TD + (c - 128)] : 0.f);
    A[r * 168 + c] = (f16)v;
  }
  int r16 = l & 15, g = l >> 4;
  f16x8 breg[2][5];
  #pragma unroll
  for (int jj = 0; jj < 2; ++jj) {
    int col = w * 32 + jj * 16 + r16;
    #pragma unroll
    for (int kk = 0; kk < 5; ++kk)
      breg[jj][kk] = *(const f16x8*)(pwT + col * 160 + kk * 32 + g * 8);
  }
  f32x4 acc[4][2];
  #pragma unroll
  for (int i = 0; i < 4; ++i)
    #pragma unroll
    for (int jj = 0; jj < 2; ++jj) acc[i][jj] = (f32x4){0.f, 0.f, 0.f, 0.f};
  __syncthreads();
  #pragma unroll
  for (int kk = 0; kk < 5; ++kk) {
    #pragma unroll
    for (int i = 0; i < 4; ++i) {
      f16x8 a = *(const f16x8*)(A + (i * 16 + r16) * 168 + kk * 32 + g * 8);
      acc[i][0] = __builtin_amdgcn_mfma_f32_16x16x32_f16(a, breg[0][kk], acc[i][0], 0, 0, 0);
      acc[i][1] = __builtin_amdgcn_mfma_f32_16x16x32_f16(a, breg[1][kk], acc[i][1], 0, 0, 0);
    }
  }
  #pragma unroll
  for (int i = 0; i < 4; ++i)
    #pragma unroll
    for (int jj = 0; jj < 2; ++jj) {
      int col = w * 32 + jj * 16 + r16;
      float bj = pb[col];
      #pragma unroll
      for (int q = 0; q < 4; ++q) {
        int row = n0 + i * 16 + g * 4 + q;
        if (row < NN) xin[(size_t)row * INC + col] = (f16)(acc[i][jj][q] + bj);
      }
    }
}

// ---------------- MFMA h1 = xin @ W1 (f16 out) + fused att1 ----------------
__global__ __launch_bounds__(256) void k_h1g(const f16* __restrict__ xin,
                                             const f16* __restrict__ W1T,
                                             const float* __restrict__ as1,
                                             const float* __restrict__ ad1,
                                             f16* __restrict__ h1,
                                             float* __restrict__ als,
                                             float* __restrict__ ald) {
  __shared__ f16 A[64 * 136];  // 64 x 128 (pad 8)
  int tid = threadIdx.x, l = tid & 63, w = tid >> 6;
  int n0 = blockIdx.x * 64;
  f16x8 zero = {};
  for (int ci = tid; ci < 1024; ci += 256) {
    int r = ci >> 4, c8 = (ci & 15) * 8;
    int n = n0 + r;
    f16x8 v = (n < NN) ? *(const f16x8*)(xin + (size_t)n * INC + c8) : zero;
    *(f16x8*)(A + r * 136 + c8) = v;
  }
  int r16 = l & 15, g = l >> 4;
  f16x8 breg[4][4];
  #pragma unroll
  for (int jj = 0; jj < 4; ++jj) {
    int col = w * 64 + jj * 16 + r16;
    #pragma unroll
    for (int kk = 0; kk < 4; ++kk)
      breg[jj][kk] = *(const f16x8*)(W1T + col * 128 + kk * 32 + g * 8);
  }
  f32x4 acc[4][4];
  #pragma unroll
  for (int i = 0; i < 4; ++i)
    #pragma unroll
    for (int jj = 0; jj < 4; ++jj) acc[i][jj] = (f32x4){0.f, 0.f, 0.f, 0.f};
  __syncthreads();
  #pragma unroll
  for (int kk = 0; kk < 4; ++kk)
    #pragma unroll
    for (int i = 0; i < 4; ++i) {
      f16x8 a = *(const f16x8*)(A + (i * 16 + r16) * 136 + kk * 32 + g * 8);
      #pragma unroll
      for (int jj = 0; jj < 4; ++jj)
        acc[i][jj] = __builtin_amdgcn_mfma_f32_16x16x32_f16(a, breg[jj][kk], acc[i][jj], 0, 0, 0);
    }
  #pragma unroll
  for (int i = 0; i < 4; ++i)
    #pragma unroll
    for (int jj = 0; jj < 4; ++jj) {
      int col = w * 64 + jj * 16 + r16;
      #pragma unroll
      for (int q = 0; q < 4; ++q) {
        int row = n0 + i * 16 + g * 4 + q;
        if (row < NN) h1[(size_t)row * H1C + col] = (f16)acc[i][jj][q];
      }
    }
  // fused att1: head w (wave w owns cols w*64..w*64+63)
  float asc[4], adc[4];
  #pragma unroll
  for (int jj = 0; jj < 4; ++jj) {
    int col = w * 64 + jj * 16 + r16;
    asc[jj] = as1[col];
    adc[jj] = ad1[col];
  }
  #pragma unroll
  for (int i = 0; i < 4; ++i)
    #pragma unroll
    for (int q = 0; q < 4; ++q) {
      float ps = 0.f, pd = 0.f;
      #pragma unroll
      for (int jj = 0; jj < 4; ++jj) {
        ps = fmaf(acc[i][jj][q], asc[jj], ps);
        pd = fmaf(acc[i][jj][q], adc[jj], pd);
      }
      #pragma unroll
      for (int o = 1; o < 16; o <<= 1) {
        ps += __shfl_xor(ps, o);
        pd += __shfl_xor(pd, o);
      }
      int row = n0 + i * 16 + g * 4 + q;
      if (r16 == 0 && row < NN) {
        als[row * 4 + w] = ps;
        ald[row * 4 + w] = pd;
      }
    }
}

// ---------------- MFMA h2 = ln1 @ W2 (f32 out) + fused att2 ----------------
__global__ __launch_bounds__(256) void k_h2g(const f16* __restrict__ ln1,
                                             const f16* __restrict__ W2T,
                                             const float* __restrict__ as2,
                                             const float* __restrict__ ad2,
                                             float* __restrict__ h2,
                                             float* __restrict__ als2,
                                             float* __restrict__ ald2) {
  __shared__ f16 A[64 * 264];  // 64 x 256 (pad 8)
  int tid = threadIdx.x, l = tid & 63, w = tid >> 6;
  int n0 = blockIdx.x * 64;
  f16x8 zero = {};
  for (int ci = tid; ci < 2048; ci += 256) {
    int r = ci >> 5, c8 = (ci & 31) * 8;
    int n = n0 + r;
    f16x8 v = (n < NN) ? *(const f16x8*)(ln1 + (size_t)n * H1C + c8) : zero;
    *(f16x8*)(A + r * 264 + c8) = v;
  }
  int r16 = l & 15, g = l >> 4;
  f16x8 breg[2][8];
  #pragma unroll
  for (int jj = 0; jj < 2; ++jj) {
    int col = jj * 16 + r16;
    #pragma unroll
    for (int kk = 0; kk < 8; ++kk)
      breg[jj][kk] = *(const f16x8*)(W2T + col * 256 + kk * 32 + g * 8);
  }
  f32x4 acc[2];
  acc[0] = (f32x4){0.f, 0.f, 0.f, 0.f};
  acc[1] = (f32x4){0.f, 0.f, 0.f, 0.f};
  __syncthreads();
  #pragma unroll
  for (int kk = 0; kk < 8; ++kk) {
    f16x8 a = *(const f16x8*)(A + (w * 16 + r16) * 264 + kk * 32 + g * 8);
    acc[0] = __builtin_amdgcn_mfma_f32_16x16x32_f16(a, breg[0][kk], acc[0], 0, 0, 0);
    acc[1] = __builtin_amdgcn_mfma_f32_16x16x32_f16(a, breg[1][kk], acc[1], 0, 0, 0);
  }
  #pragma unroll
  for (int jj = 0; jj < 2; ++jj)
    #pragma unroll
    for (int q = 0; q < 4; ++q) {
      int row = n0 + w * 16 + g * 4 + q;
      int col = jj * 16 + r16;
      if (row < NN) h2[(size_t)row * OUTC + col] = acc[jj][q];
    }
  // fused att2 (single head; 16 lanes hold a full 32-ch row)
  float as_0 = as2[r16], as_1 = as2[16 + r16];
  float ad_0 = ad2[r16], ad_1 = ad2[16 + r16];
  #pragma unroll
  for (int q = 0; q < 4; ++q) {
    float ps = acc[0][q] * as_0 + acc[1][q] * as_1;
    float pd = acc[0][q] * ad_0 + acc[1][q] * ad_1;
    #pragma unroll
    for (int o = 1; o < 16; o <<= 1) {
      ps += __shfl_xor(ps, o);
      pd += __shfl_xor(pd, o);
    }
    int row = n0 + w * 16 + g * 4 + q;
    if (r16 == 0 && row < NN) {
      als2[row] = ps;
      ald2[row] = pd;
    }
  }
}

// ---------------- layer-1: fused score+aggregate+bias+ELU+LN, 2-edge ILP ----------------
__global__ __launch_bounds__(256) void k_agg1(
    const int* __restrict__ rowst, const int* __restrict__ src_sorted,
    const f16* __restrict__ h1, const float* __restrict__ als,
    const float* __restrict__ ald, const float* __restrict__ b1,
    const float* __restrict__ g1, const float* __restrict__ be1,
    f16* __restrict__ ln1) {
  __shared__ int s_s[4][64];
  __shared__ float s_e[4][256];
  int tid = threadIdx.x, wid = tid >> 6, lane = tid & 63;
  int n = blockIdx.x * 4 + wid;
  int k0 = rowst[n], k1 = rowst[n + 1];
  const float4 adv = *(const float4*)(ald + n * 4);
  const float4 asv = *(const float4*)(als + n * 4);
  float se0 = __expf(leaky(asv.x + adv.x));
  float se1 = __expf(leaky(asv.y + adv.y));
  float se2 = __expf(leaky(asv.z + adv.z));
  float se3 = __expf(leaky(asv.w + adv.w));
  int half = lane >> 5, l32 = lane & 31;
  int hh = l32 >> 3;      // head for my 8-ch block
  int c0 = l32 * 8;
  float acc[8];
  #pragma unroll
  for (int u = 0; u < 8; ++u) acc[u] = 0.f;
  float d0 = 0.f, d1 = 0.f, d2 = 0.f, d3 = 0.f;
  for (int base = k0; base < k1; base += 64) {
    int p = base + lane;
    int sv = 0;
    float4 e4 = {0.f, 0.f, 0.f, 0.f};
    if (p < k1) {
      sv = src_sorted[p];
      const float4 a = *(const float4*)(als + sv * 4);
      e4.x = __expf(leaky(a.x + adv.x));
      e4.y = __expf(leaky(a.y + adv.y));
      e4.z = __expf(leaky(a.z + adv.z));
      e4.w = __expf(leaky(a.w + adv.w));
    }
    s_s[wid][lane] = sv;
    *(float4*)(&s_e[wid][lane * 4]) = e4;
    d0 += e4.x; d1 += e4.y; d2 += e4.z; d3 += e4.w;
    int lim = k1 - base;
    if (lim > 64) lim = 64;
    #pragma unroll 2
    for (int j = half; j < lim; j += 2) {
      int s = s_s[wid][j];
      float aa = s_e[wid][j * 4 + hh];
      f16x8 hg = *(const f16x8*)(h1 + (size_t)s * H1C + c0);
      #pragma unroll
      for (int u = 0; u < 8; ++u) acc[u] = fmaf((float)hg[u], aa, acc[u]);
    }
  }
  #pragma unroll
  for (int o = 32; o >= 1; o >>= 1) {
    d0 += __shfl_xor(d0, o); d1 += __shfl_xor(d1, o);
    d2 += __shfl_xor(d2, o); d3 += __shfl_xor(d3, o);
  }
  d0 += se0; d1 += se1; d2 += se2; d3 += se3;
  // merge halves
  #pragma unroll
  for (int u = 0; u < 8; ++u) acc[u] += __shfl_xor(acc[u], 32);
  float dh = hh == 0 ? d0 : hh == 1 ? d1 : hh == 2 ? d2 : d3;
  float seh = hh == 0 ? se0 : hh == 1 ? se1 : hh == 2 ? se2 : se3;
  float invd = 1.f / dh;
  f16x8 hv = *(const f16x8*)(h1 + (size_t)n * H1C + c0);
  const float4 ba = *(const float4*)(b1 + c0), bb = *(const float4*)(b1 + c0 + 4);
  float v[8];
  #pragma unroll
  for (int u = 0; u < 8; ++u) {
    float bu = u < 4 ? (&ba.x)[u] : (&bb.x)[u - 4];
    float t = fmaf((float)hv[u], seh, acc[u]);
    t = fmaf(t, invd, bu);
    v[u] = t > 0.f ? t : expm1f(t);
  }
  float s1 = 0.f, s2 = 0.f;
  #pragma unroll
  for (int u = 0; u < 8; ++u) { s1 += v[u]; s2 += v[u] * v[u]; }
  #pragma unroll
  for (int o = 16; o >= 1; o >>= 1) {
    s1 += __shfl_xor(s1, o, 32);
    s2 += __shfl_xor(s2, o, 32);
  }
  float mu = s1 * (1.f / 256.f);
  float var = s2 * (1.f / 256.f) - mu * mu;
  float sc = rsqrtf(var + 1e-5f);
  if (half == 0) {
    const float4 ga = *(const float4*)(g1 + c0), gb = *(const float4*)(g1 + c0 + 4);
    const float4 ea = *(const float4*)(be1 + c0), eb = *(const float4*)(be1 + c0 + 4);
    f16x8 o8;
    #pragma unroll
    for (int u = 0; u < 8; ++u) {
      float gu = u < 4 ? (&ga.x)[u] : (&gb.x)[u - 4];
      float eu = u < 4 ? (&ea.x)[u] : (&eb.x)[u - 4];
      o8[u] = (f16)((v[u] - mu) * sc * gu + eu);
    }
    *(f16x8*)(ln1 + (size_t)n * H1C + c0) = o8;
  }
}

// ---------------- layer-2: fused score+aggregate+bias+LN -> out, 4-edge ILP ----------------
__global__ __launch_bounds__(256) void k_agg2(
    const int* __restrict__ rowst, const int* __restrict__ src_sorted,
    const float* __restrict__ h2, const float* __restrict__ als2,
    const float* __restrict__ ald2, const float* __restrict__ b2,
    const float* __restrict__ g2, const float* __restrict__ be2,
    float* __restrict__ out) {
  __shared__ int s_s[4][64];
  __shared__ float s_e[4][64];
  int tid = threadIdx.x, wid = tid >> 6, lane = tid & 63;
  int n = blockIdx.x * 4 + wid;
  int k0 = rowst[n], k1 = rowst[n + 1];
  float adn = ald2[n];
  float se = __expf(leaky(als2[n] + adn));
  int q = lane >> 4, l16 = lane & 15;
  int c0 = l16 * 2;
  float a0 = 0.f, a1 = 0.f, d = 0.f;
  for (int base = k0; base < k1; base += 64) {
    int p = base + lane;
    int sv = 0;
    float e = 0.f;
    if (p < k1) {
      sv = src_sorted[p];
      e = __expf(leaky(als2[sv] + adn));
    }
    s_s[wid][lane] = sv;
    s_e[wid][lane] = e;
    d += e;
    int lim = k1 - base;
    if (lim > 64) lim = 64;
    #pragma unroll 2
    for (int j = q; j < lim; j += 4) {
      int s = s_s[wid][j];
      float aa = s_e[wid][j];
      float2 hg = *(const float2*)(h2 + (size_t)s * OUTC + c0);
      a0 = fmaf(hg.x, aa, a0);
      a1 = fmaf(hg.y, aa, a1);
    }
  }
  #pragma unroll
  for (int o = 32; o >= 1; o >>= 1) d += __shfl_xor(d, o);
  d += se;
  float invd = 1.f / d;
  a0 += __shfl_xor(a0, 16); a1 += __shfl_xor(a1, 16);
  a0 += __shfl_xor(a0, 32); a1 += __shfl_xor(a1, 32);
  float2 hn = *(const float2*)(h2 + (size_t)n * OUTC + c0);
  float t0 = fmaf(fmaf(hn.x, se, a0), invd, b2[c0]);
  float t1 = fmaf(fmaf(hn.y, se, a1), invd, b2[c0 + 1]);
  float s1 = t0 + t1, s2 = t0 * t0 + t1 * t1;
  #pragma unroll
  for (int o = 8; o >= 1; o >>= 1) {
    s1 += __shfl_xor(s1, o, 16);
    s2 += __shfl_xor(s2, o, 16);
  }
  float mu = s1 * (1.f / 32.f);
  float var = s2 * (1.f / 32.f) - mu * mu;
  float sc = rsqrtf(var + 1e-5f);
  if (q == 0) {
    float2 o2;
    o2.x = (t0 - mu) * sc * g2[c0] + be2[c0];
    o2.y = (t1 - mu) * sc * g2[c0 + 1] + be2[c0 + 1];
    *(float2*)(out + (size_t)n * OUTC + c0) = o2;
  }
}

extern "C" void kernel_launch(void* const* d_in, const int* in_sizes, int n_in,
                              void* d_out, int out_size, void* d_ws, size_t ws_size,
                              hipStream_t stream) {
  const float* x   = (const float*)d_in[0];
  const int*   ei  = (const int*)d_in[1];
  const float* et  = (const float*)d_in[2];
  const float* tw  = (const float*)d_in[3];
  const float* tb  = (const float*)d_in[4];
  const float* pw  = (const float*)d_in[5];
  const float* pb  = (const float*)d_in[6];
  const float* W1  = (const float*)d_in[7];
  const float* as1 = (const float*)d_in[8];
  const float* ad1 = (const float*)d_in[9];
  const float* b1  = (const float*)d_in[10];
  const float* g1  = (const float*)d_in[11];
  const float* be1 = (const float*)d_in[12];
  const float* W2  = (const float*)d_in[13];
  const float* as2 = (const float*)d_in[14];
  const float* ad2 = (const float*)d_in[15];
  const float* b2  = (const float*)d_in[16];
  const float* g2  = (const float*)d_in[17];
  const float* be2 = (const float*)d_in[18];

  char* ws = (char*)d_ws;
  size_t off = 0;
  auto alloc = [&](size_t bytes) {
    void* p = ws + off;
    off += (bytes + 255) & ~(size_t)255;
    return p;
  };
  float* node_time = (float*)alloc((size_t)NN * TD * 4);
  f16* xin   = (f16*)alloc((size_t)NN * INC * 2);
  f16* h1    = (f16*)alloc((size_t)NN * H1C * 2);
  f16* ln1   = (f16*)alloc((size_t)NN * H1C * 2);
  float* h2  = (float*)alloc((size_t)NN * OUTC * 4);
  float* als1v = (float*)alloc((size_t)NN * 4 * 4);
  float* ald1v = (float*)alloc((size_t)NN * 4 * 4);
  float* als2v = (float*)alloc((size_t)NN * 4);
  float* ald2v = (float*)alloc((size_t)NN * 4);
  float* et_sorted = (float*)alloc((size_t)EE * 4);
  f16* W1T = (f16*)alloc(32768 * 2);
  f16* pwT = (f16*)alloc(20480 * 2);
  f16* W2T = (f16*)alloc(8192 * 2);
  int* deg2 = (int*)alloc((size_t)NN * 2 * 4);
  int* deg_dst = deg2;
  int* deg_src = deg2 + NN;
  int* rowst_dst = (int*)alloc((size_t)(NN + 1) * 4);
  int* rowst_src = (int*)alloc((size_t)(NN + 1) * 4);
  int* fill_dst = (int*)alloc((size_t)NN * 4);
  int* fill_src = (int*)alloc((size_t)NN * 4);
  int* src_sorted = (int*)alloc((size_t)EE * 4);
  int* bsum_d = (int*)alloc(64 * 4);
  int* bsum_s = (int*)alloc(64 * 4);

  hipMemsetAsync(deg2, 0, (size_t)NN * 2 * 4, stream);

  const int NB = (NN + 1023) / 1024;  // 49
  const int NT64 = (NN + 63) / 64;    // 782
  k_deg_prep<<<(EE + 61440 + 255) / 256, 256, 0, stream>>>(ei, deg_dst, deg_src, W1, pw,
                                                           W2, W1T, pwT, W2T);
  k_scan1<<<dim3(NB, 2), 1024, 0, stream>>>(deg_dst, deg_src, rowst_dst, rowst_src,
                                            bsum_d, bsum_s);
  k_scan3<<<dim3((NN + 255) / 256, 2), 256, 0, stream>>>(rowst_dst, rowst_src, bsum_d,
                                                         bsum_s, fill_dst, fill_src);
  k_scatter<<<(EE + 255) / 256, 256, 0, stream>>>(ei, et, fill_dst, fill_src,
                                                  src_sorted, et_sorted);
  k_time_agg<<<NN / 4, 256, 0, stream>>>(rowst_src, et_sorted, tw, tb, node_time);
  k_projg<<<NT64, 256, 0, stream>>>(x, node_time, pwT, pb, xin);
  k_h1g<<<NT64, 256, 0, stream>>>(xin, W1T, as1, ad1, h1, als1v, ald1v);
  k_agg1<<<NN / 4, 256, 0, stream>>>(rowst_dst, src_sorted, h1, als1v, ald1v,
                                     b1, g1, be1, ln1);
  k_h2g<<<NT64, 256, 0, stream>>>(ln1, W2T, as2, ad2, h2, als2v, ald2v);
  k_agg2<<<NN / 4, 256, 0, stream>>>(rowst_dst, src_sorted, h2, als2v, ald2v,
                                     b2, g2, be2, (float*)d_out);
}